// Round 11
// baseline (145.701 us; speedup 1.0000x reference)
//
#include <hip/hip_runtime.h>
#include <hip/hip_bf16.h>
#include <math.h>

#define B_  16
#define L_  8192
#define DH_ 256
#define T_  512
#define DG_ 512
#define DP_ 256

typedef __attribute__((ext_vector_type(8))) short short8b;
typedef __attribute__((ext_vector_type(4))) float f32x4;

typedef const __attribute__((address_space(1))) void gas_t;
typedef __attribute__((address_space(3))) void las_t;
#define GLOAD_LDS16(g, l) __builtin_amdgcn_global_load_lds((gas_t*)(g), (las_t*)(l), 16, 0, 0)

// Compaction metadata (module-scope device memory; rewritten every launch).
__device__ int g_cnt[B_];
__device__ int g_src[B_][L_];

static __device__ __forceinline__ short f2bf(float f) {
    union { __hip_bfloat16 b; short s; } u;
    u.b = __float2bfloat16(f);
    return u.s;
}

static __device__ __forceinline__ float bf2f(short s) {
    union { float f; unsigned u; } v;
    v.u = ((unsigned)(unsigned short)s) << 16;
    return v.f;
}

static __device__ __forceinline__ unsigned cvtpk_bf16(float lo, float hi) {
    unsigned r;
    asm("v_cvt_pk_bf16_f32 %0, %1, %2" : "=v"(r) : "v"(lo), "v"(hi));
    return r;
}

static __device__ __forceinline__ float exp2_raw(float x) {
    float r;
    asm("v_exp_f32 %0, %1" : "=v"(r) : "v"(x));
    return r;
}

static __device__ __forceinline__ short8b cvt8(const float* __restrict__ src) {
    float4 a = *(const float4*)src;
    float4 b = *(const float4*)(src + 4);
    short8b o;
    o[0] = f2bf(a.x); o[1] = f2bf(a.y); o[2] = f2bf(a.z); o[3] = f2bf(a.w);
    o[4] = f2bf(b.x); o[5] = f2bf(b.y); o[6] = f2bf(b.z); o[7] = f2bf(b.w);
    return o;
}

// ---------------------------------------------------------------------------
// prep_all: one launch for the three tiny prep jobs.
//  blocks 0..15  : scan_mask (per-batch compaction), 1024 thr
//  blocks 16..23 : wk_to_fragT (Wk^T B-frags, 128 frags)
//  blocks 24..39 : w_to_frag<DG> for Wq (alpha folded, 256 frags)
// ---------------------------------------------------------------------------
__global__ __launch_bounds__(1024) void prep_all(const int* __restrict__ mask,
                                                 const float* __restrict__ Wk,
                                                 const float* __restrict__ Wq,
                                                 short* __restrict__ Wktf,
                                                 short* __restrict__ Wqf,
                                                 float alpha_q) {
    const int blk = blockIdx.x;
    const int tid = threadIdx.x, lane = tid & 63;
    const int l15 = lane & 15, g = lane >> 4;

    if (blk < 16) {
        const int b = blk, wid = tid >> 6;
        __shared__ int wsum[16];
        const int* mb = mask + (size_t)b * L_;
        int base = 0;
        for (int it = 0; it < L_ / 1024; ++it) {
            const int l = it * 1024 + tid;
            const int um = (mb[l] == 0);
            unsigned long long bal = __ballot(um);
            const int below = __popcll(bal & ((1ull << lane) - 1ull));
            const int wtot  = __popcll(bal);
            if (lane == 0) wsum[wid] = wtot;
            __syncthreads();
            int wbase = 0, tot = 0;
#pragma unroll
            for (int w = 0; w < 16; ++w) {
                wbase += (w < wid) ? wsum[w] : 0;
                tot   += wsum[w];
            }
            if (um) g_src[b][base + wbase + below] = l;
            base += tot;
            __syncthreads();
        }
        if (tid == 0) g_cnt[b] = base;
    } else if (blk < 24) {
        // Wk^T B-frags: frag f = nf*8+ks, elem j = Wk[ks*32+g*8+j][nf*16+l15]
        const int f = (blk - 16) * 16 + (tid >> 6);   // 0..127
        const int nf = f >> 3, ks = f & 7;
        short8b o;
#pragma unroll
        for (int j = 0; j < 8; ++j)
            o[j] = f2bf(Wk[(size_t)(ks * 32 + g * 8 + j) * DH_ + nf * 16 + l15]);
        *(short8b*)&Wktf[(size_t)f * 512 + lane * 8] = o;
    } else {
        // Wq B-frags (alpha_q folded): frag f = nf*16+ks
        const int f = (blk - 24) * 16 + (tid >> 6);   // 0..255
        const int nf = f >> 4, ks = f & 15;
        const float* src = Wq + (size_t)(nf * 16 + l15) * DG_ + ks * 32 + g * 8;
        short8b o;
#pragma unroll
        for (int j = 0; j < 8; ++j) o[j] = f2bf(src[j] * alpha_q);
        *(short8b*)&Wqf[(size_t)f * 512 + lane * 8] = o;
    }
}

// ---------------------------------------------------------------------------
// projQfused: Qc = bf16( bf16(alpha*G@Wq^T) @ Wk )  [8192 x 256], one kernel.
// Phase 1: 64-row G tile -> acc (MFMA, Wqf B-frags from L2).
// Phase 2: bf16 C -> padded LDS (stride 264 shorts = 528B -> 4-bank rotation);
//          each wave re-reads ONLY its own 16 rows as A-frags.
// Phase 3: second MFMA vs Wktf, store Qc. Two bf16 roundings, same as before.
// ---------------------------------------------------------------------------
__global__ __launch_bounds__(256) void projQfused(const float* __restrict__ G,
                                                  const short* __restrict__ Wqf,
                                                  const short* __restrict__ Wktf,
                                                  short* __restrict__ Qc) {
    __shared__ short sQ[64 * 264];

    const int tid = threadIdx.x, wid = tid >> 6, lane = tid & 63;
    const int l15 = lane & 15, g = lane >> 4;
    const size_t m0 = (size_t)blockIdx.x * 64;

    // ---- phase 1: Q = alpha * G @ Wq^T ----
    const float* arow = G + (m0 + wid * 16 + l15) * DG_;
    short8b af[16];
#pragma unroll
    for (int ks = 0; ks < 16; ++ks) {
        float4 a = *(const float4*)&arow[ks * 32 + g * 8];
        float4 c = *(const float4*)&arow[ks * 32 + g * 8 + 4];
        short8b o;
        o[0] = f2bf(a.x); o[1] = f2bf(a.y); o[2] = f2bf(a.z); o[3] = f2bf(a.w);
        o[4] = f2bf(c.x); o[5] = f2bf(c.y); o[6] = f2bf(c.z); o[7] = f2bf(c.w);
        af[ks] = o;
    }
    f32x4 acc[16];
#pragma unroll
    for (int i = 0; i < 16; ++i) acc[i] = (f32x4){0.f, 0.f, 0.f, 0.f};
#pragma unroll
    for (int ks = 0; ks < 16; ++ks)
#pragma unroll
        for (int nf = 0; nf < 16; ++nf) {
            short8b wf = *(const short8b*)&Wqf[(size_t)(nf * 16 + ks) * 512 + lane * 8];
            acc[nf] = __builtin_amdgcn_mfma_f32_16x16x32_bf16(af[ks], wf, acc[nf], 0, 0, 0);
        }

    // ---- phase 2: C -> LDS (row-major, padded) ----
#pragma unroll
    for (int nf = 0; nf < 16; ++nf)
#pragma unroll
        for (int r = 0; r < 4; ++r)
            sQ[(wid * 16 + 4 * g + r) * 264 + nf * 16 + l15] = f2bf(acc[nf][r]);
    __syncthreads();

    // ---- phase 3: Qc = Q @ Wk ----
    short8b af2[8];
#pragma unroll
    for (int ks = 0; ks < 8; ++ks)
        af2[ks] = *(const short8b*)&sQ[(wid * 16 + l15) * 264 + ks * 32 + g * 8];
    f32x4 acc2[16];
#pragma unroll
    for (int i = 0; i < 16; ++i) acc2[i] = (f32x4){0.f, 0.f, 0.f, 0.f};
#pragma unroll
    for (int ks = 0; ks < 8; ++ks)
#pragma unroll
        for (int nf = 0; nf < 16; ++nf) {
            short8b wf = *(const short8b*)&Wktf[(size_t)(nf * 8 + ks) * 512 + lane * 8];
            acc2[nf] = __builtin_amdgcn_mfma_f32_16x16x32_bf16(af2[ks], wf, acc2[nf], 0, 0, 0);
        }
#pragma unroll
    for (int nf = 0; nf < 16; ++nf)
#pragma unroll
        for (int r = 0; r < 4; ++r)
            Qc[(m0 + wid * 16 + 4 * g + r) * DP_ + nf * 16 + l15] = f2bf(acc2[nf][r]);
}

// ---------------------------------------------------------------------------
// gather_h: pure data movement. 64 rows/block (LDS 32 KB -> 4 blocks/CU for
// gather-latency hiding). Gathered H rows -> swizzled LDS -> Hcf frag-tiled
// + Htc transposed.
// Hcf : tile(l>>4)[4096]: ((d>>5)*4+((d>>3)&3))*128 + (l&15)*8 + (d&7)
// Htc : tile(l>>5)[8192]: d*32 + ((l>>3)&3)*8 + (l&7)
// ---------------------------------------------------------------------------
__global__ __launch_bounds__(256, 4) void gather_h(const float* __restrict__ H,
                                                   short* __restrict__ Hcf,
                                                   short* __restrict__ Htc) {
    __shared__ short sH_[16384];   // 32768 bytes = 64 rows x 512 B

    const int tid = threadIdx.x, wid = tid >> 6;
    const int b  = blockIdx.x >> 7;
    const int c0 = (blockIdx.x & 127) * 64;

    const int cnt    = g_cnt[b];
    const int padded = (cnt + 31) & ~31;
    if (c0 >= padded) return;

    // ---- stage 64 gathered rows -> swizzled sH ----
    {
        const int r = tid >> 2, sub = tid & 3;
        const int ld = c0 + r;
        const bool real = (ld < cnt);
        const float* src = real ? (H + ((size_t)b * L_ + g_src[b][ld]) * DH_) : nullptr;
#pragma unroll
        for (int j = 0; j < 8; ++j) {
            const int c = sub * 8 + j;            // 16B chunk 0..31
            short8b o;
            if (real) o = cvt8(&src[c * 8]);
            else {
#pragma unroll
                for (int k = 0; k < 8; ++k) o[k] = 0;
            }
            const int byteoff = r * 512 + ((c * 16) ^ ((r & 7) << 4));
            *(short8b*)((char*)sH_ + byteoff) = o;
        }
    }
    __syncthreads();

    // ---- Hcf: frag-linear LDS reads, coalesced 16B global stores ----
    short* kb = Hcf + (size_t)b * (L_ * DP_) + (size_t)(c0 >> 4) * 4096;
#pragma unroll
    for (int mt = 0; mt < 4; ++mt) {
#pragma unroll
        for (int cc = 0; cc < 2; ++cc) {
            const int c    = tid + cc * 256;      // chunk 0..511
            const int l15  = c & 15;
            const int frag = c >> 4;
            const int dby  = 2 * ((frag >> 2) * 32 + (frag & 3) * 8);
            const int row  = mt * 16 + l15;
            short8b v = *(const short8b*)((char*)sH_ + row * 512 + (dby ^ ((row & 7) << 4)));
            *(short8b*)&kb[mt * 4096 + c * 8] = v;
        }
    }

    // ---- Htc transpose from swizzled sH ----
    short* Htcb = Htc + (size_t)b * (DH_ * L_);
#pragma unroll
    for (int u = 0; u < 8; ++u) {
        const int d  = (tid & 63) + (u & 3) * 64;
        const int lg = wid * 2 + (u >> 2);        // 8-row group 0..7
        short8b o;
#pragma unroll
        for (int j = 0; j < 8; ++j) {
            const int row = lg * 8 + j;
            o[j] = *(const short*)((char*)sH_ + row * 512 + ((2 * d) ^ ((row & 7) << 4)));
        }
        *(short8b*)&Htcb[((size_t)(c0 >> 5) + (lg >> 2)) * 8192 + d * 32 + (lg & 3) * 8] = o;
    }
}

// ---------------------------------------------------------------------------
// attn_pipe4<LSPLIT>: unchanged pipeline; partials now written as bf16.
// ---------------------------------------------------------------------------
template <int LSPLIT>
__global__ __launch_bounds__(256, 2) void attn_pipe4(const short* __restrict__ Kfc,
                                                     const short* __restrict__ Qb,
                                                     const short* __restrict__ Htc,
                                                     float* __restrict__ Zdirect,
                                                     short* __restrict__ Zp,
                                                     float* __restrict__ Sp) {
    constexpr int LSB = (LSPLIT == 8) ? 3 : (LSPLIT == 4) ? 2 : (LSPLIT == 2) ? 1 : 0;

    __shared__ short sbuf[2][16384];

    const int wg   = blockIdx.x;
    const int low  = wg & 7;
    const int rest = wg >> 3;
    const int tg   = rest & 3;
    const int ghi  = rest >> 2;
    const int grp  = ghi * 8 + low;
    const int b    = grp >> LSB;
    const int lq   = grp & (LSPLIT - 1);

    const int tid  = threadIdx.x;
    const int wid  = tid >> 6;
    const int lane = tid & 63;
    const int l15  = lane & 15, g = lane >> 4;
    const int th   = wid;
    const int t0   = tg * 128;

    const int cnt      = g_cnt[b];
    const int nt_total = (cnt + 31) >> 5;
    const int q        = (nt_total + LSPLIT - 1) >> LSB;
    const int start    = lq * q;
    int ntiles = nt_total - start;
    ntiles = ntiles < 0 ? 0 : (ntiles > q ? q : ntiles);

    const short* Kfb  = Kfc + (size_t)b * (L_ * DP_);
    const short* Htfb = Htc + (size_t)b * (DH_ * L_);

    short8b qf[2][8];
#pragma unroll
    for (int nt = 0; nt < 2; ++nt) {
        const short* qrow = Qb + ((size_t)b * T_ + t0 + th * 32 + nt * 16 + l15) * DP_;
#pragma unroll
        for (int ks = 0; ks < 8; ++ks)
            qf[nt][ks] = *(const short8b*)&qrow[ks * 32 + g * 8];
    }

    f32x4 zacc[2][16];
#pragma unroll
    for (int nt = 0; nt < 2; ++nt)
#pragma unroll
        for (int nf = 0; nf < 16; ++nf)
            zacc[nt][nf] = (f32x4){0.f, 0.f, 0.f, 0.f};
    float s_part[2] = {0.f, 0.f};

    const int  idx0  = (l15 + 32 * (g & 1)) * 4;
    const int  idx1  = idx0 + 64;
    const bool ltsel = (g >> 1) != 0;

    auto STAGE = [&](int bi, int gi) {
        const int gic = gi < 255 ? gi : 255;
        const short* kg = Kfb  + (size_t)gic * 8192;
        const short* hg = Htfb + (size_t)gic * 8192;
        const short* base = (wid < 2) ? (kg + wid * 4096) : (hg + (wid - 2) * 4096);
        short* dst = &sbuf[bi][wid * 4096];
#pragma unroll
        for (int c = 0; c < 8; ++c)
            GLOAD_LDS16(base + c * 512 + lane * 8, dst + c * 512);
    };

    if (ntiles > 0) {
        STAGE(0, start);
        asm volatile("s_waitcnt vmcnt(0)" ::: "memory");
        __builtin_amdgcn_s_barrier();
        STAGE(1, start + 1);

        for (int i = 0; i < ntiles; ++i) {
            const int cur = i & 1;
            const short* sK = &sbuf[cur][0];
            const short* sH = &sbuf[cur][8192];
            const int gi = start + i;
            const int limit = cnt - (gi << 5);

            f32x4 sv[2][2];
#pragma unroll
            for (int lt = 0; lt < 2; ++lt)
#pragma unroll
                for (int nt = 0; nt < 2; ++nt)
                    sv[lt][nt] = (f32x4){0.f, 0.f, 0.f, 0.f};
            __builtin_amdgcn_s_setprio(1);
#pragma unroll
            for (int lt = 0; lt < 2; ++lt) {
                const short* tile = sK + lt * 4096;
#pragma unroll
                for (int ks = 0; ks < 8; ++ks) {
                    short8b kf = *(const short8b*)&tile[ks * 512 + g * 128 + l15 * 8];
                    sv[lt][0] = __builtin_amdgcn_mfma_f32_16x16x32_bf16(kf, qf[0][ks], sv[lt][0], 0, 0, 0);
                    sv[lt][1] = __builtin_amdgcn_mfma_f32_16x16x32_bf16(kf, qf[1][ks], sv[lt][1], 0, 0, 0);
                }
            }
            __builtin_amdgcn_s_setprio(0);

            unsigned pk[2][2][2];
            if (limit >= 32) {
#pragma unroll
                for (int lt = 0; lt < 2; ++lt)
#pragma unroll
                    for (int nt = 0; nt < 2; ++nt) {
                        float p0 = exp2_raw(sv[lt][nt][0]);
                        float p1 = exp2_raw(sv[lt][nt][1]);
                        float p2 = exp2_raw(sv[lt][nt][2]);
                        float p3 = exp2_raw(sv[lt][nt][3]);
                        s_part[nt] += (p0 + p1) + (p2 + p3);
                        pk[lt][nt][0] = cvtpk_bf16(p0, p1);
                        pk[lt][nt][1] = cvtpk_bf16(p2, p3);
                    }
            } else {
#pragma unroll
                for (int lt = 0; lt < 2; ++lt) {
                    const int thr = limit - lt * 16 - 4 * g;
                    float madd[4];
#pragma unroll
                    for (int r = 0; r < 4; ++r) madd[r] = (r < thr) ? 0.f : -INFINITY;
#pragma unroll
                    for (int nt = 0; nt < 2; ++nt) {
                        float p0 = exp2_raw(sv[lt][nt][0] + madd[0]);
                        float p1 = exp2_raw(sv[lt][nt][1] + madd[1]);
                        float p2 = exp2_raw(sv[lt][nt][2] + madd[2]);
                        float p3 = exp2_raw(sv[lt][nt][3] + madd[3]);
                        s_part[nt] += (p0 + p1) + (p2 + p3);
                        pk[lt][nt][0] = cvtpk_bf16(p0, p1);
                        pk[lt][nt][1] = cvtpk_bf16(p2, p3);
                    }
                }
            }

            short8b pa[2];
#pragma unroll
            for (int nt = 0; nt < 2; ++nt) {
                int A0 = __builtin_amdgcn_ds_bpermute(idx0, (int)pk[0][nt][0]);
                int A1 = __builtin_amdgcn_ds_bpermute(idx0, (int)pk[0][nt][1]);
                int B0 = __builtin_amdgcn_ds_bpermute(idx0, (int)pk[1][nt][0]);
                int B1 = __builtin_amdgcn_ds_bpermute(idx0, (int)pk[1][nt][1]);
                int C0 = __builtin_amdgcn_ds_bpermute(idx1, (int)pk[0][nt][0]);
                int C1 = __builtin_amdgcn_ds_bpermute(idx1, (int)pk[0][nt][1]);
                int D0 = __builtin_amdgcn_ds_bpermute(idx1, (int)pk[1][nt][0]);
                int D1 = __builtin_amdgcn_ds_bpermute(idx1, (int)pk[1][nt][1]);
                union { int d[4]; short8b v; } u;
                u.d[0] = ltsel ? B0 : A0;
                u.d[1] = ltsel ? B1 : A1;
                u.d[2] = ltsel ? D0 : C0;
                u.d[3] = ltsel ? D1 : C1;
                pa[nt] = u.v;
            }

            __builtin_amdgcn_s_setprio(1);
#pragma unroll
            for (int nf = 0; nf < 16; ++nf) {
                short8b hb = *(const short8b*)&sH[nf * 512 + l15 * 32 + g * 8];
                zacc[0][nf] = __builtin_amdgcn_mfma_f32_16x16x32_bf16(pa[0], hb, zacc[0][nf], 0, 0, 0);
                zacc[1][nf] = __builtin_amdgcn_mfma_f32_16x16x32_bf16(pa[1], hb, zacc[1][nf], 0, 0, 0);
            }
            __builtin_amdgcn_s_setprio(0);

            asm volatile("s_waitcnt vmcnt(0)" ::: "memory");
            __builtin_amdgcn_s_barrier();
            if (i + 2 < ntiles) STAGE(cur, gi + 2);
        }
    }

    float sful[2];
#pragma unroll
    for (int nt = 0; nt < 2; ++nt) {
        float v = s_part[nt];
        v += __shfl_xor(v, 16, 64);
        v += __shfl_xor(v, 32, 64);
        sful[nt] = v;
    }

    if constexpr (LSPLIT == 1) {
#pragma unroll
        for (int nt = 0; nt < 2; ++nt)
#pragma unroll
            for (int r = 0; r < 4; ++r) {
                float s = __shfl(sful[nt], 4 * g + r, 64);
                float ri = (s > 0.f) ? 1.f / s : 0.f;
                float* zrow = Zdirect + ((size_t)b * T_ + t0 + th * 32 + nt * 16 + 4 * g + r) * DH_;
#pragma unroll
                for (int nf = 0; nf < 16; ++nf)
                    zrow[nf * 16 + l15] = zacc[nt][nf][r] * ri;
            }
    } else {
        const int pb = (b * 4 + tg) * LSPLIT + lq;
        if (lane < 16) {
            Sp[(size_t)pb * 128 + th * 32 + l15]      = sful[0];
            Sp[(size_t)pb * 128 + th * 32 + 16 + l15] = sful[1];
        }
        // bf16 partials (always written, even when ntiles==0 -> zeros)
#pragma unroll
        for (int nt = 0; nt < 2; ++nt)
#pragma unroll
            for (int r = 0; r < 4; ++r) {
                short* zrow = Zp + ((size_t)pb * 128 + th * 32 + nt * 16 + 4 * g + r) * DH_;
#pragma unroll
                for (int nf = 0; nf < 16; ++nf)
                    zrow[nf * 16 + l15] = f2bf(zacc[nt][nf][r]);
            }
    }
}

// ---------------------------------------------------------------------------
// combine_z<LSPLIT>: Z = sum_lq Zp / sum_lq Sp. bf16 partials, 8 d/thread.
// ---------------------------------------------------------------------------
template <int LSPLIT>
__global__ __launch_bounds__(256) void combine_z(const short* __restrict__ Zp,
                                                 const float* __restrict__ Sp,
                                                 float* __restrict__ Z) {
    const int idx8 = blockIdx.x * 256 + threadIdx.x;   // one per 8 d
    const int d0 = (idx8 & 31) * 8;
    const int t  = (idx8 >> 5) & 511;
    const int b  = idx8 >> 14;
    const int tg = t >> 7, tl = t & 127;
    const size_t pb0 = (size_t)(b * 4 + tg) * LSPLIT;

    float acc[8] = {0.f, 0.f, 0.f, 0.f, 0.f, 0.f, 0.f, 0.f};
    float s = 0.f;
#pragma unroll
    for (int lq = 0; lq < LSPLIT; ++lq) {
        short8b v = *(const short8b*)&Zp[((pb0 + lq) * 128 + tl) * 256 + d0];
#pragma unroll
        for (int j = 0; j < 8; ++j) acc[j] += bf2f(v[j]);
        s += Sp[(pb0 + lq) * 128 + tl];
    }
    const float ri = (s > 0.f) ? 1.f / s : 0.f;
    float* zrow = Z + (((size_t)b * T_ + t) * DH_ + d0);
    *(float4*)zrow       = make_float4(acc[0] * ri, acc[1] * ri, acc[2] * ri, acc[3] * ri);
    *(float4*)(zrow + 4) = make_float4(acc[4] * ri, acc[5] * ri, acc[6] * ri, acc[7] * ri);
}

// ---------------------------------------------------------------------------
extern "C" void kernel_launch(void* const* d_in, const int* in_sizes, int n_in,
                              void* d_out, int out_size, void* d_ws, size_t ws_size,
                              hipStream_t stream) {
    const float* H    = (const float*)d_in[0];
    const float* G    = (const float*)d_in[1];
    const int*   mask = (const int*)d_in[2];
    const float* Wk   = (const float*)d_in[3];
    const float* Wq   = (const float*)d_in[4];
    float* Z = (float*)d_out;

    short* Wktf = (short*)d_ws;                 //   128 KB (Wk^T B-frags)
    short* Wqf  = Wktf + 65536ull;              //   256 KB
    short* Hcf  = Wqf + 131072ull;              //  67.1 MB (frag-tiled bf16 H)
    short* Qc   = Hcf + 33554432ull;            //   4.2 MB
    short* Htc  = Qc + 2097152ull;              //  67.1 MB (transposed bf16 H)
    short* Zpb  = Htc + 33554432ull;            //  bf16 partials (LSPLIT*16.8MB)

    const float alpha_q = 1.4426950408889634f / 16.0f;  // DP^-0.5 * log2(e)

    prep_all<<<dim3(40), 1024, 0, stream>>>(mask, Wk, Wq, Wktf, Wqf, alpha_q);
    projQfused<<<dim3(B_ * T_ / 64), 256, 0, stream>>>(G, Wqf, Wktf, Qc);
    gather_h<<<dim3(B_ * 128), 256, 0, stream>>>(H, Hcf, Htc);

    const size_t base = 138805248ull;  // bytes up to Zpb (same anchor as R9/R10)
    if (ws_size >= base + 8388608ull * 8 + 262144ull) {
        float* Sp = (float*)(Zpb + (size_t)64 * 8 * 128 * 256);
        attn_pipe4<8><<<dim3(512), 256, 0, stream>>>(Hcf, Qc, Htc, Z, Zpb, Sp);
        combine_z<8><<<dim3(1024), 256, 0, stream>>>(Zpb, Sp, Z);
    } else if (ws_size >= base + 8388608ull * 4 + 131072ull) {
        float* Sp = (float*)(Zpb + (size_t)64 * 4 * 128 * 256);
        attn_pipe4<4><<<dim3(256), 256, 0, stream>>>(Hcf, Qc, Htc, Z, Zpb, Sp);
        combine_z<4><<<dim3(1024), 256, 0, stream>>>(Zpb, Sp, Z);
    } else if (ws_size >= base + 8388608ull * 2 + 65536ull) {
        float* Sp = (float*)(Zpb + (size_t)64 * 2 * 128 * 256);
        attn_pipe4<2><<<dim3(128), 256, 0, stream>>>(Hcf, Qc, Htc, Z, Zpb, Sp);
        combine_z<2><<<dim3(1024), 256, 0, stream>>>(Zpb, Sp, Z);
    } else {
        attn_pipe4<1><<<dim3(64), 256, 0, stream>>>(Hcf, Qc, Htc, Z, Zpb, nullptr);
    }
}

// Round 13
// 128.276 us; speedup vs baseline: 1.1358x; 1.1358x over previous
//
#include <hip/hip_runtime.h>
#include <hip/hip_bf16.h>
#include <math.h>

#define B_  16
#define L_  8192
#define DH_ 256
#define T_  512
#define DG_ 512
#define DP_ 256

typedef __attribute__((ext_vector_type(8))) short short8b;
typedef __attribute__((ext_vector_type(4))) short short4b;
typedef __attribute__((ext_vector_type(4))) float f32x4;

typedef const __attribute__((address_space(1))) void gas_t;
typedef __attribute__((address_space(3))) void las_t;
typedef __attribute__((address_space(3))) short lds_short;
#define GLOAD_LDS16(g, l) __builtin_amdgcn_global_load_lds((gas_t*)(g), (las_t*)(l), 16, 0, 0)

// tr-read semantics (m156/m162): each lane reads 8B at its OWN address; HW
// redistributes within each 16-lane group: out lane l elem j = the group's
// 64-elem block element (l&15)+j*16. So lane addr MUST be
// subtile_base + (lane&15)*8 bytes (R12 bug: this term was missing).
#define TRR(dst, P, OFF) \
    asm volatile("ds_read_b64_tr_b16 %0, %1 offset:%c2" : "=v"(dst) : "v"(P), "i"(OFF))

// Compaction metadata (module-scope device memory; rewritten every launch).
__device__ int g_cnt[B_];
__device__ int g_src[B_][L_];

static __device__ __forceinline__ short f2bf(float f) {
    union { __hip_bfloat16 b; short s; } u;
    u.b = __float2bfloat16(f);
    return u.s;
}

static __device__ __forceinline__ float bf2f(short s) {
    union { float f; unsigned u; } v;
    v.u = ((unsigned)(unsigned short)s) << 16;
    return v.f;
}

static __device__ __forceinline__ unsigned cvtpk_bf16(float lo, float hi) {
    unsigned r;
    asm("v_cvt_pk_bf16_f32 %0, %1, %2" : "=v"(r) : "v"(lo), "v"(hi));
    return r;
}

static __device__ __forceinline__ float exp2_raw(float x) {
    float r;
    asm("v_exp_f32 %0, %1" : "=v"(r) : "v"(x));
    return r;
}

static __device__ __forceinline__ short8b cvt8(const float* __restrict__ src) {
    float4 a = *(const float4*)src;
    float4 b = *(const float4*)(src + 4);
    short8b o;
    o[0] = f2bf(a.x); o[1] = f2bf(a.y); o[2] = f2bf(a.z); o[3] = f2bf(a.w);
    o[4] = f2bf(b.x); o[5] = f2bf(b.y); o[6] = f2bf(b.z); o[7] = f2bf(b.w);
    return o;
}

// ---------------------------------------------------------------------------
// prep_all (unchanged — passing)
// ---------------------------------------------------------------------------
__global__ __launch_bounds__(1024) void prep_all(const int* __restrict__ mask,
                                                 const float* __restrict__ Wk,
                                                 const float* __restrict__ Wq,
                                                 short* __restrict__ Wktf,
                                                 short* __restrict__ Wqf,
                                                 float alpha_q) {
    const int blk = blockIdx.x;
    const int tid = threadIdx.x, lane = tid & 63;
    const int l15 = lane & 15, g = lane >> 4;

    if (blk < 16) {
        const int b = blk, wid = tid >> 6;
        __shared__ int wsum[16];
        const int* mb = mask + (size_t)b * L_;
        int base = 0;
        for (int it = 0; it < L_ / 1024; ++it) {
            const int l = it * 1024 + tid;
            const int um = (mb[l] == 0);
            unsigned long long bal = __ballot(um);
            const int below = __popcll(bal & ((1ull << lane) - 1ull));
            const int wtot  = __popcll(bal);
            if (lane == 0) wsum[wid] = wtot;
            __syncthreads();
            int wbase = 0, tot = 0;
#pragma unroll
            for (int w = 0; w < 16; ++w) {
                wbase += (w < wid) ? wsum[w] : 0;
                tot   += wsum[w];
            }
            if (um) g_src[b][base + wbase + below] = l;
            base += tot;
            __syncthreads();
        }
        if (tid == 0) g_cnt[b] = base;
    } else if (blk < 24) {
        const int f = (blk - 16) * 16 + (tid >> 6);   // 0..127
        const int nf = f >> 3, ks = f & 7;
        short8b o;
#pragma unroll
        for (int j = 0; j < 8; ++j)
            o[j] = f2bf(Wk[(size_t)(ks * 32 + g * 8 + j) * DH_ + nf * 16 + l15]);
        *(short8b*)&Wktf[(size_t)f * 512 + lane * 8] = o;
    } else {
        const int f = (blk - 24) * 16 + (tid >> 6);   // 0..255
        const int nf = f >> 4, ks = f & 15;
        const float* src = Wq + (size_t)(nf * 16 + l15) * DG_ + ks * 32 + g * 8;
        short8b o;
#pragma unroll
        for (int j = 0; j < 8; ++j) o[j] = f2bf(src[j] * alpha_q);
        *(short8b*)&Wqf[(size_t)f * 512 + lane * 8] = o;
    }
}

// ---------------------------------------------------------------------------
// projQfused (unchanged — passing): Qc = bf16(bf16(aG@Wq^T)@Wk)
// ---------------------------------------------------------------------------
__global__ __launch_bounds__(256) void projQfused(const float* __restrict__ G,
                                                  const short* __restrict__ Wqf,
                                                  const short* __restrict__ Wktf,
                                                  short* __restrict__ Qc) {
    __shared__ short sQ[64 * 264];

    const int tid = threadIdx.x, wid = tid >> 6, lane = tid & 63;
    const int l15 = lane & 15, g = lane >> 4;
    const size_t m0 = (size_t)blockIdx.x * 64;

    const float* arow = G + (m0 + wid * 16 + l15) * DG_;
    short8b af[16];
#pragma unroll
    for (int ks = 0; ks < 16; ++ks) {
        float4 a = *(const float4*)&arow[ks * 32 + g * 8];
        float4 c = *(const float4*)&arow[ks * 32 + g * 8 + 4];
        short8b o;
        o[0] = f2bf(a.x); o[1] = f2bf(a.y); o[2] = f2bf(a.z); o[3] = f2bf(a.w);
        o[4] = f2bf(c.x); o[5] = f2bf(c.y); o[6] = f2bf(c.z); o[7] = f2bf(c.w);
        af[ks] = o;
    }
    f32x4 acc[16];
#pragma unroll
    for (int i = 0; i < 16; ++i) acc[i] = (f32x4){0.f, 0.f, 0.f, 0.f};
#pragma unroll
    for (int ks = 0; ks < 16; ++ks)
#pragma unroll
        for (int nf = 0; nf < 16; ++nf) {
            short8b wf = *(const short8b*)&Wqf[(size_t)(nf * 16 + ks) * 512 + lane * 8];
            acc[nf] = __builtin_amdgcn_mfma_f32_16x16x32_bf16(af[ks], wf, acc[nf], 0, 0, 0);
        }
#pragma unroll
    for (int nf = 0; nf < 16; ++nf)
#pragma unroll
        for (int r = 0; r < 4; ++r)
            sQ[(wid * 16 + 4 * g + r) * 264 + nf * 16 + l15] = f2bf(acc[nf][r]);
    __syncthreads();

    short8b af2[8];
#pragma unroll
    for (int ks = 0; ks < 8; ++ks)
        af2[ks] = *(const short8b*)&sQ[(wid * 16 + l15) * 264 + ks * 32 + g * 8];
    f32x4 acc2[16];
#pragma unroll
    for (int i = 0; i < 16; ++i) acc2[i] = (f32x4){0.f, 0.f, 0.f, 0.f};
#pragma unroll
    for (int ks = 0; ks < 8; ++ks)
#pragma unroll
        for (int nf = 0; nf < 16; ++nf) {
            short8b wf = *(const short8b*)&Wktf[(size_t)(nf * 8 + ks) * 512 + lane * 8];
            acc2[nf] = __builtin_amdgcn_mfma_f32_16x16x32_bf16(af2[ks], wf, acc2[nf], 0, 0, 0);
        }
#pragma unroll
    for (int nf = 0; nf < 16; ++nf)
#pragma unroll
        for (int r = 0; r < 4; ++r)
            Qc[(m0 + wid * 16 + 4 * g + r) * DP_ + nf * 16 + l15] = f2bf(acc2[nf][r]);
}

// ---------------------------------------------------------------------------
// gather_h2 (unchanged from R12): gathered H rows -> subtiled LDS -> linear
// stores. Hsub per-b: tile(l>>6)*16384 shorts; within tile:
// (l>>2)*1024 + (d>>4)*64 + (l&3)*16 + (d&15). Pad rows zeroed.
// ---------------------------------------------------------------------------
__global__ __launch_bounds__(256, 4) void gather_h2(const float* __restrict__ H,
                                                    short* __restrict__ Hsb) {
    __shared__ short sT[16384];

    const int tid = threadIdx.x;
    const int b  = blockIdx.x >> 7;
    const int c0 = (blockIdx.x & 127) * 64;

    const int cnt = g_cnt[b];
    if (c0 >= ((cnt + 63) & ~63)) return;

    {
        const int r = tid >> 2, sub = tid & 3;
        const int ld = c0 + r;
        const bool real = (ld < cnt);
        const float* src = real ? (H + ((size_t)b * L_ + g_src[b][ld]) * DH_) : nullptr;
#pragma unroll
        for (int j = 0; j < 8; ++j) {
            const int c = sub * 8 + j;
            short8b o;
            if (real) o = cvt8(&src[c * 8]);
            else {
#pragma unroll
                for (int k = 0; k < 8; ++k) o[k] = 0;
            }
            const int off = (r >> 2) * 1024 + (c >> 1) * 64 + (r & 3) * 16 + (c & 1) * 8;
            *(short8b*)&sT[off] = o;
        }
    }
    __syncthreads();

    short* dst = Hsb + (size_t)b * (L_ * DH_) + (size_t)(c0 >> 6) * 16384;
#pragma unroll
    for (int k = 0; k < 8; ++k) {
        const int idx = k * 2048 + tid * 8;
        *(short8b*)&dst[idx] = *(const short8b*)&sT[idx];
    }
}

// ---------------------------------------------------------------------------
// attn_pipe5<LSPLIT>: single-copy flash attention (R12 + tr-read addr fix).
// ---------------------------------------------------------------------------
template <int LSPLIT>
__global__ __launch_bounds__(256, 2) void attn_pipe5(const short* __restrict__ Hsb,
                                                     const short* __restrict__ Qb,
                                                     float* __restrict__ Zdirect,
                                                     short* __restrict__ Zp,
                                                     float* __restrict__ Sp) {
    constexpr int LSB = (LSPLIT == 8) ? 3 : (LSPLIT == 4) ? 2 : (LSPLIT == 2) ? 1 : 0;

    __shared__ short sbuf[2][16384];

    const int wg   = blockIdx.x;
    const int low  = wg & 7;
    const int rest = wg >> 3;
    const int tg   = rest & 3;
    const int ghi  = rest >> 2;
    const int grp  = ghi * 8 + low;
    const int b    = grp >> LSB;
    const int lq   = grp & (LSPLIT - 1);

    const int tid  = threadIdx.x;
    const int wid  = tid >> 6;
    const int lane = tid & 63;
    const int l15  = lane & 15, g = lane >> 4;
    const int th   = wid;
    const int t0   = tg * 128;

    const int cnt      = g_cnt[b];
    const int nt_total = (cnt + 63) >> 6;
    const int q        = (nt_total + LSPLIT - 1) >> LSB;
    const int start    = lq * q;
    int ntiles = nt_total - start;
    ntiles = ntiles < 0 ? 0 : (ntiles > q ? q : ntiles);

    const short* Hb = Hsb + (size_t)b * (L_ * DH_);

    short8b qf[2][8];
#pragma unroll
    for (int nt = 0; nt < 2; ++nt) {
        const short* qrow = Qb + ((size_t)b * T_ + t0 + th * 32 + nt * 16 + l15) * DP_;
#pragma unroll
        for (int ks = 0; ks < 8; ++ks)
            qf[nt][ks] = *(const short8b*)&qrow[ks * 32 + g * 8];
    }

    f32x4 zacc[2][16];
#pragma unroll
    for (int nt = 0; nt < 2; ++nt)
#pragma unroll
        for (int nf = 0; nf < 16; ++nf)
            zacc[nt][nf] = (f32x4){0.f, 0.f, 0.f, 0.f};
    float s_part[2] = {0.f, 0.f};

    const int  idx0  = (l15 + 32 * (g & 1)) * 4;
    const int  idx1  = idx0 + 64;
    const bool ltsel = (g >> 1) != 0;

    // tr-read per-lane base: group offset (g*2048 shorts = subtile ls=2g)
    // PLUS the per-lane (lane&15)*4 shorts = 8 bytes (R12's missing term).
    lds_short* trb0 = (lds_short*)&sbuf[0][0] + (lane >> 4) * 2048 + (lane & 15) * 4;
    lds_short* trb1 = (lds_short*)&sbuf[1][0] + (lane >> 4) * 2048 + (lane & 15) * 4;

    auto STAGE = [&](int bi, int gi) {
        const int gic = gi < 127 ? gi : 127;
        const short* src = Hb + (size_t)gic * 16384;
#pragma unroll
        for (int c = 0; c < 8; ++c) {
            const int u = wid * 512 + c * 64 + lane;
            GLOAD_LDS16(src + u * 8, &sbuf[bi][u * 8]);
        }
    };

    if (ntiles > 0) {
        STAGE(0, start);
        asm volatile("s_waitcnt vmcnt(0)" ::: "memory");
        __builtin_amdgcn_s_barrier();
        STAGE(1, start + 1);

        for (int i = 0; i < ntiles; ++i) {
            const int cur = i & 1;
            const short* sK = &sbuf[cur][0];
            const int gi = start + i;
            const int limit = cnt - (gi << 6);

            // ---- S^T phase (two halves) ----
            unsigned pk[4][2][2];
#pragma unroll
            for (int lh2 = 0; lh2 < 2; ++lh2) {
                f32x4 sv[2][2];
#pragma unroll
                for (int ltl = 0; ltl < 2; ++ltl)
#pragma unroll
                    for (int nt = 0; nt < 2; ++nt)
                        sv[ltl][nt] = (f32x4){0.f, 0.f, 0.f, 0.f};
                __builtin_amdgcn_s_setprio(1);
#pragma unroll
                for (int ltl = 0; ltl < 2; ++ltl) {
                    const int lt = lh2 * 2 + ltl;
#pragma unroll
                    for (int ks = 0; ks < 8; ++ks) {
                        short8b af = *(const short8b*)&sK[(lt * 4 + (l15 >> 2)) * 1024 +
                                                          (ks * 2 + (g >> 1)) * 64 +
                                                          (l15 & 3) * 16 + (g & 1) * 8];
                        sv[ltl][0] = __builtin_amdgcn_mfma_f32_16x16x32_bf16(af, qf[0][ks], sv[ltl][0], 0, 0, 0);
                        sv[ltl][1] = __builtin_amdgcn_mfma_f32_16x16x32_bf16(af, qf[1][ks], sv[ltl][1], 0, 0, 0);
                    }
                }
                __builtin_amdgcn_s_setprio(0);

                if (limit >= 64) {
#pragma unroll
                    for (int ltl = 0; ltl < 2; ++ltl)
#pragma unroll
                        for (int nt = 0; nt < 2; ++nt) {
                            float p0 = exp2_raw(sv[ltl][nt][0]);
                            float p1 = exp2_raw(sv[ltl][nt][1]);
                            float p2 = exp2_raw(sv[ltl][nt][2]);
                            float p3 = exp2_raw(sv[ltl][nt][3]);
                            s_part[nt] += (p0 + p1) + (p2 + p3);
                            pk[lh2 * 2 + ltl][nt][0] = cvtpk_bf16(p0, p1);
                            pk[lh2 * 2 + ltl][nt][1] = cvtpk_bf16(p2, p3);
                        }
                } else {
#pragma unroll
                    for (int ltl = 0; ltl < 2; ++ltl) {
                        const int lt = lh2 * 2 + ltl;
                        const int thr = limit - lt * 16 - 4 * g;
                        float madd[4];
#pragma unroll
                        for (int r = 0; r < 4; ++r) madd[r] = (r < thr) ? 0.f : -INFINITY;
#pragma unroll
                        for (int nt = 0; nt < 2; ++nt) {
                            float p0 = exp2_raw(sv[ltl][nt][0] + madd[0]);
                            float p1 = exp2_raw(sv[ltl][nt][1] + madd[1]);
                            float p2 = exp2_raw(sv[ltl][nt][2] + madd[2]);
                            float p3 = exp2_raw(sv[ltl][nt][3] + madd[3]);
                            s_part[nt] += (p0 + p1) + (p2 + p3);
                            pk[lt][nt][0] = cvtpk_bf16(p0, p1);
                            pk[lt][nt][1] = cvtpk_bf16(p2, p3);
                        }
                    }
                }
            }

            // ---- P -> PV A-frags ----
            short8b pa[2][2];
#pragma unroll
            for (int h = 0; h < 2; ++h)
#pragma unroll
                for (int nt = 0; nt < 2; ++nt) {
                    int A0 = __builtin_amdgcn_ds_bpermute(idx0, (int)pk[2 * h][nt][0]);
                    int A1 = __builtin_amdgcn_ds_bpermute(idx0, (int)pk[2 * h][nt][1]);
                    int B0 = __builtin_amdgcn_ds_bpermute(idx0, (int)pk[2 * h + 1][nt][0]);
                    int B1 = __builtin_amdgcn_ds_bpermute(idx0, (int)pk[2 * h + 1][nt][1]);
                    int C0 = __builtin_amdgcn_ds_bpermute(idx1, (int)pk[2 * h][nt][0]);
                    int C1 = __builtin_amdgcn_ds_bpermute(idx1, (int)pk[2 * h][nt][1]);
                    int D0 = __builtin_amdgcn_ds_bpermute(idx1, (int)pk[2 * h + 1][nt][0]);
                    int D1 = __builtin_amdgcn_ds_bpermute(idx1, (int)pk[2 * h + 1][nt][1]);
                    union { int d[4]; short8b v; } u;
                    u.d[0] = ltsel ? B0 : A0;
                    u.d[1] = ltsel ? B1 : A1;
                    u.d[2] = ltsel ? D0 : C0;
                    u.d[3] = ltsel ? D1 : C1;
                    pa[h][nt] = u.v;
                }

            // ---- PV: tr-read pipelined (2 deep) ----
            lds_short* ptr = cur ? trb1 : trb0;
            short4b tb[2][4];
            TRR(tb[0][0], ptr, 0 * 2048);
            TRR(tb[0][1], ptr, 1 * 2048);
            TRR(tb[0][2], ptr, 8 * 2048);
            TRR(tb[0][3], ptr, 9 * 2048);
            __builtin_amdgcn_s_setprio(1);
#pragma unroll
            for (int nf = 0; nf < 16; ++nf) {
                if (nf < 15) {
                    TRR(tb[(nf + 1) & 1][0], ptr, 0 * 2048 + (nf + 1) * 128);
                    TRR(tb[(nf + 1) & 1][1], ptr, 1 * 2048 + (nf + 1) * 128);
                    TRR(tb[(nf + 1) & 1][2], ptr, 8 * 2048 + (nf + 1) * 128);
                    TRR(tb[(nf + 1) & 1][3], ptr, 9 * 2048 + (nf + 1) * 128);
                    asm volatile("s_waitcnt lgkmcnt(4)" ::: "memory");
                } else {
                    asm volatile("s_waitcnt lgkmcnt(0)" ::: "memory");
                }
                __builtin_amdgcn_sched_barrier(0);
#pragma unroll
                for (int h = 0; h < 2; ++h) {
                    short8b hb = __builtin_shufflevector(tb[nf & 1][2 * h], tb[nf & 1][2 * h + 1],
                                                         0, 1, 2, 3, 4, 5, 6, 7);
                    zacc[0][nf] = __builtin_amdgcn_mfma_f32_16x16x32_bf16(pa[h][0], hb, zacc[0][nf], 0, 0, 0);
                    zacc[1][nf] = __builtin_amdgcn_mfma_f32_16x16x32_bf16(pa[h][1], hb, zacc[1][nf], 0, 0, 0);
                }
            }
            __builtin_amdgcn_s_setprio(0);

            asm volatile("s_waitcnt vmcnt(0)" ::: "memory");
            __builtin_amdgcn_s_barrier();
            if (i + 2 < ntiles) STAGE(cur, gi + 2);
        }
    }

    // ---- epilogue ----
    float sful[2];
#pragma unroll
    for (int nt = 0; nt < 2; ++nt) {
        float v = s_part[nt];
        v += __shfl_xor(v, 16, 64);
        v += __shfl_xor(v, 32, 64);
        sful[nt] = v;
    }

    if constexpr (LSPLIT == 1) {
#pragma unroll
        for (int nt = 0; nt < 2; ++nt)
#pragma unroll
            for (int r = 0; r < 4; ++r) {
                float s = __shfl(sful[nt], 4 * g + r, 64);
                float ri = (s > 0.f) ? 1.f / s : 0.f;
                float* zrow = Zdirect + ((size_t)b * T_ + t0 + th * 32 + nt * 16 + 4 * g + r) * DH_;
#pragma unroll
                for (int nf = 0; nf < 16; ++nf)
                    zrow[nf * 16 + l15] = zacc[nt][nf][r] * ri;
            }
    } else {
        const int pb = (b * 4 + tg) * LSPLIT + lq;
        if (lane < 16) {
            Sp[(size_t)pb * 128 + th * 32 + l15]      = sful[0];
            Sp[(size_t)pb * 128 + th * 32 + 16 + l15] = sful[1];
        }
#pragma unroll
        for (int nt = 0; nt < 2; ++nt)
#pragma unroll
            for (int r = 0; r < 4; ++r) {
                short* zrow = Zp + ((size_t)pb * 128 + th * 32 + nt * 16 + 4 * g + r) * DH_;
#pragma unroll
                for (int nf = 0; nf < 16; ++nf)
                    zrow[nf * 16 + l15] = f2bf(zacc[nt][nf][r]);
            }
    }
}

// ---------------------------------------------------------------------------
// combine_z<LSPLIT> (unchanged — passing)
// ---------------------------------------------------------------------------
template <int LSPLIT>
__global__ __launch_bounds__(256) void combine_z(const short* __restrict__ Zp,
                                                 const float* __restrict__ Sp,
                                                 float* __restrict__ Z) {
    const int idx8 = blockIdx.x * 256 + threadIdx.x;
    const int d0 = (idx8 & 31) * 8;
    const int t  = (idx8 >> 5) & 511;
    const int b  = idx8 >> 14;
    const int tg = t >> 7, tl = t & 127;
    const size_t pb0 = (size_t)(b * 4 + tg) * LSPLIT;

    float acc[8] = {0.f, 0.f, 0.f, 0.f, 0.f, 0.f, 0.f, 0.f};
    float s = 0.f;
#pragma unroll
    for (int lq = 0; lq < LSPLIT; ++lq) {
        short8b v = *(const short8b*)&Zp[((pb0 + lq) * 128 + tl) * 256 + d0];
#pragma unroll
        for (int j = 0; j < 8; ++j) acc[j] += bf2f(v[j]);
        s += Sp[(pb0 + lq) * 128 + tl];
    }
    const float ri = (s > 0.f) ? 1.f / s : 0.f;
    float* zrow = Z + (((size_t)b * T_ + t) * DH_ + d0);
    *(float4*)zrow       = make_float4(acc[0] * ri, acc[1] * ri, acc[2] * ri, acc[3] * ri);
    *(float4*)(zrow + 4) = make_float4(acc[4] * ri, acc[5] * ri, acc[6] * ri, acc[7] * ri);
}

// ---------------------------------------------------------------------------
extern "C" void kernel_launch(void* const* d_in, const int* in_sizes, int n_in,
                              void* d_out, int out_size, void* d_ws, size_t ws_size,
                              hipStream_t stream) {
    const float* H    = (const float*)d_in[0];
    const float* G    = (const float*)d_in[1];
    const int*   mask = (const int*)d_in[2];
    const float* Wk   = (const float*)d_in[3];
    const float* Wq   = (const float*)d_in[4];
    float* Z = (float*)d_out;

    short* Wktf = (short*)d_ws;                 //   128 KB (Wk^T B-frags)
    short* Wqf  = Wktf + 65536ull;              //   256 KB
    short* Hsb  = Wqf + 131072ull;              //  67.1 MB (subtiled bf16 H, compacted)
    short* Qc   = Hsb + 33554432ull;            //   4.2 MB
    short* Htc  = Qc + 2097152ull;              //  67.1 MB (UNUSED — layout anchor)
    short* Zpb  = Htc + 33554432ull;            //  bf16 partials (LSPLIT*16.8MB)

    const float alpha_q = 1.4426950408889634f / 16.0f;  // DP^-0.5 * log2(e)

    prep_all<<<dim3(40), 1024, 0, stream>>>(mask, Wk, Wq, Wktf, Wqf, alpha_q);
    projQfused<<<dim3(B_ * T_ / 64), 256, 0, stream>>>(G, Wqf, Wktf, Qc);
    gather_h2<<<dim3(B_ * 128), 256, 0, stream>>>(H, Hsb);

    const size_t base = 138805248ull;  // bytes up to Zpb (same anchor as R9-R12)
    if (ws_size >= base + 8388608ull * 8 + 262144ull) {
        float* Sp = (float*)(Zpb + (size_t)64 * 8 * 128 * 256);
        attn_pipe5<8><<<dim3(512), 256, 0, stream>>>(Hsb, Qc, Z, Zpb, Sp);
        combine_z<8><<<dim3(1024), 256, 0, stream>>>(Zpb, Sp, Z);
    } else if (ws_size >= base + 8388608ull * 4 + 131072ull) {
        float* Sp = (float*)(Zpb + (size_t)64 * 4 * 128 * 256);
        attn_pipe5<4><<<dim3(256), 256, 0, stream>>>(Hsb, Qc, Z, Zpb, Sp);
        combine_z<4><<<dim3(1024), 256, 0, stream>>>(Zpb, Sp, Z);
    } else if (ws_size >= base + 8388608ull * 2 + 65536ull) {
        float* Sp = (float*)(Zpb + (size_t)64 * 2 * 128 * 256);
        attn_pipe5<2><<<dim3(128), 256, 0, stream>>>(Hsb, Qc, Z, Zpb, Sp);
        combine_z<2><<<dim3(1024), 256, 0, stream>>>(Zpb, Sp, Z);
    } else {
        attn_pipe5<1><<<dim3(64), 256, 0, stream>>>(Hsb, Qc, Z, Zpb, nullptr);
    }
}

// Round 14
// 105.028 us; speedup vs baseline: 1.3873x; 1.2213x over previous
//
#include <hip/hip_runtime.h>
#include <hip/hip_bf16.h>
#include <math.h>

#define B_  16
#define L_  8192
#define DH_ 256
#define T_  512
#define DG_ 512
#define DP_ 256

typedef __attribute__((ext_vector_type(8))) short short8b;
typedef __attribute__((ext_vector_type(4))) short short4b;
typedef __attribute__((ext_vector_type(4))) float f32x4;

typedef const __attribute__((address_space(1))) void gas_t;
typedef __attribute__((address_space(3))) void las_t;
typedef __attribute__((address_space(3))) short lds_short;
#define GLOAD_LDS16(g, l) __builtin_amdgcn_global_load_lds((gas_t*)(g), (las_t*)(l), 16, 0, 0)

// tr-read semantics (m156/m162): each lane reads 8B at its OWN address
// (subtile_base + (lane&15)*8 bytes); HW redistributes within each 16-lane
// group: out lane l elem j = the group's 64-elem block element (l&15)+j*16.
#define TRR(dst, P, OFF) \
    asm volatile("ds_read_b64_tr_b16 %0, %1 offset:%c2" : "=v"(dst) : "v"(P), "i"(OFF))

// Compaction metadata (module-scope device memory; rewritten every launch).
__device__ int g_cnt[B_];
__device__ int g_src[B_][L_];

static __device__ __forceinline__ short f2bf(float f) {
    union { __hip_bfloat16 b; short s; } u;
    u.b = __float2bfloat16(f);
    return u.s;
}

static __device__ __forceinline__ float bf2f(short s) {
    union { float f; unsigned u; } v;
    v.u = ((unsigned)(unsigned short)s) << 16;
    return v.f;
}

static __device__ __forceinline__ unsigned cvtpk_bf16(float lo, float hi) {
    unsigned r;
    asm("v_cvt_pk_bf16_f32 %0, %1, %2" : "=v"(r) : "v"(lo), "v"(hi));
    return r;
}

static __device__ __forceinline__ float exp2_raw(float x) {
    float r;
    asm("v_exp_f32 %0, %1" : "=v"(r) : "v"(x));
    return r;
}

static __device__ __forceinline__ short8b cvt8(const float* __restrict__ src) {
    float4 a = *(const float4*)src;
    float4 b = *(const float4*)(src + 4);
    short8b o;
    o[0] = f2bf(a.x); o[1] = f2bf(a.y); o[2] = f2bf(a.z); o[3] = f2bf(a.w);
    o[4] = f2bf(b.x); o[5] = f2bf(b.y); o[6] = f2bf(b.z); o[7] = f2bf(b.w);
    return o;
}

// ---------------------------------------------------------------------------
// prep_all (unchanged — passing)
// ---------------------------------------------------------------------------
__global__ __launch_bounds__(1024) void prep_all(const int* __restrict__ mask,
                                                 const float* __restrict__ Wk,
                                                 const float* __restrict__ Wq,
                                                 short* __restrict__ Wktf,
                                                 short* __restrict__ Wqf,
                                                 float alpha_q) {
    const int blk = blockIdx.x;
    const int tid = threadIdx.x, lane = tid & 63;
    const int l15 = lane & 15, g = lane >> 4;

    if (blk < 16) {
        const int b = blk, wid = tid >> 6;
        __shared__ int wsum[16];
        const int* mb = mask + (size_t)b * L_;
        int base = 0;
        for (int it = 0; it < L_ / 1024; ++it) {
            const int l = it * 1024 + tid;
            const int um = (mb[l] == 0);
            unsigned long long bal = __ballot(um);
            const int below = __popcll(bal & ((1ull << lane) - 1ull));
            const int wtot  = __popcll(bal);
            if (lane == 0) wsum[wid] = wtot;
            __syncthreads();
            int wbase = 0, tot = 0;
#pragma unroll
            for (int w = 0; w < 16; ++w) {
                wbase += (w < wid) ? wsum[w] : 0;
                tot   += wsum[w];
            }
            if (um) g_src[b][base + wbase + below] = l;
            base += tot;
            __syncthreads();
        }
        if (tid == 0) g_cnt[b] = base;
    } else if (blk < 24) {
        const int f = (blk - 16) * 16 + (tid >> 6);   // 0..127
        const int nf = f >> 3, ks = f & 7;
        short8b o;
#pragma unroll
        for (int j = 0; j < 8; ++j)
            o[j] = f2bf(Wk[(size_t)(ks * 32 + g * 8 + j) * DH_ + nf * 16 + l15]);
        *(short8b*)&Wktf[(size_t)f * 512 + lane * 8] = o;
    } else {
        const int f = (blk - 24) * 16 + (tid >> 6);   // 0..255
        const int nf = f >> 4, ks = f & 15;
        const float* src = Wq + (size_t)(nf * 16 + l15) * DG_ + ks * 32 + g * 8;
        short8b o;
#pragma unroll
        for (int j = 0; j < 8; ++j) o[j] = f2bf(src[j] * alpha_q);
        *(short8b*)&Wqf[(size_t)f * 512 + lane * 8] = o;
    }
}

// ---------------------------------------------------------------------------
// produce_all: MERGED projQfused (blocks 0..127) + gather_h2 (blocks 128+).
// Both depend only on prep_all; merging lets projQ's 128 blocks co-execute
// with the 2048 gather blocks instead of running as a serial epoch.
// Shared LDS: max(16896 shorts projQ, 16384 shorts gather) = 16896.
// ---------------------------------------------------------------------------
__global__ __launch_bounds__(256) void produce_all(const float* __restrict__ G,
                                                   const short* __restrict__ Wqf,
                                                   const short* __restrict__ Wktf,
                                                   short* __restrict__ Qc,
                                                   const float* __restrict__ H,
                                                   short* __restrict__ Hsb) {
    __shared__ short sL[16896];

    const int blk = blockIdx.x;
    const int tid = threadIdx.x;

    if (blk < 128) {
        // ---- projQfused path: Qc = bf16(bf16(aG@Wq^T)@Wk) ----
        const int wid = tid >> 6, lane = tid & 63;
        const int l15 = lane & 15, g = lane >> 4;
        const size_t m0 = (size_t)blk * 64;

        const float* arow = G + (m0 + wid * 16 + l15) * DG_;
        short8b af[16];
#pragma unroll
        for (int ks = 0; ks < 16; ++ks) {
            float4 a = *(const float4*)&arow[ks * 32 + g * 8];
            float4 c = *(const float4*)&arow[ks * 32 + g * 8 + 4];
            short8b o;
            o[0] = f2bf(a.x); o[1] = f2bf(a.y); o[2] = f2bf(a.z); o[3] = f2bf(a.w);
            o[4] = f2bf(c.x); o[5] = f2bf(c.y); o[6] = f2bf(c.z); o[7] = f2bf(c.w);
            af[ks] = o;
        }
        f32x4 acc[16];
#pragma unroll
        for (int i = 0; i < 16; ++i) acc[i] = (f32x4){0.f, 0.f, 0.f, 0.f};
#pragma unroll
        for (int ks = 0; ks < 16; ++ks)
#pragma unroll
            for (int nf = 0; nf < 16; ++nf) {
                short8b wf = *(const short8b*)&Wqf[(size_t)(nf * 16 + ks) * 512 + lane * 8];
                acc[nf] = __builtin_amdgcn_mfma_f32_16x16x32_bf16(af[ks], wf, acc[nf], 0, 0, 0);
            }
#pragma unroll
        for (int nf = 0; nf < 16; ++nf)
#pragma unroll
            for (int r = 0; r < 4; ++r)
                sL[(wid * 16 + 4 * g + r) * 264 + nf * 16 + l15] = f2bf(acc[nf][r]);
        __syncthreads();

        short8b af2[8];
#pragma unroll
        for (int ks = 0; ks < 8; ++ks)
            af2[ks] = *(const short8b*)&sL[(wid * 16 + l15) * 264 + ks * 32 + g * 8];
        f32x4 acc2[16];
#pragma unroll
        for (int i = 0; i < 16; ++i) acc2[i] = (f32x4){0.f, 0.f, 0.f, 0.f};
#pragma unroll
        for (int ks = 0; ks < 8; ++ks)
#pragma unroll
            for (int nf = 0; nf < 16; ++nf) {
                short8b wf = *(const short8b*)&Wktf[(size_t)(nf * 8 + ks) * 512 + lane * 8];
                acc2[nf] = __builtin_amdgcn_mfma_f32_16x16x32_bf16(af2[ks], wf, acc2[nf], 0, 0, 0);
            }
#pragma unroll
        for (int nf = 0; nf < 16; ++nf)
#pragma unroll
            for (int r = 0; r < 4; ++r)
                Qc[(m0 + wid * 16 + 4 * g + r) * DP_ + nf * 16 + l15] = f2bf(acc2[nf][r]);
    } else {
        // ---- gather_h2 path: gathered H rows -> subtiled LDS -> linear store.
        // Hsub per-b: tile(l>>6)*16384 shorts; within tile:
        // (l>>2)*1024 + (d>>4)*64 + (l&3)*16 + (d&15). Pad rows zeroed.
        const int gb = blk - 128;
        const int b  = gb >> 7;
        const int c0 = (gb & 127) * 64;

        const int cnt = g_cnt[b];
        if (c0 >= ((cnt + 63) & ~63)) return;

        {
            const int r = tid >> 2, sub = tid & 3;
            const int ld = c0 + r;
            const bool real = (ld < cnt);
            const float* src = real ? (H + ((size_t)b * L_ + g_src[b][ld]) * DH_) : nullptr;
#pragma unroll
            for (int j = 0; j < 8; ++j) {
                const int c = j * 4 + sub;   // row's 4 threads read 64B contiguous per j
                short8b o;
                if (real) o = cvt8(&src[c * 8]);
                else {
#pragma unroll
                    for (int k = 0; k < 8; ++k) o[k] = 0;
                }
                const int off = (r >> 2) * 1024 + (c >> 1) * 64 + (r & 3) * 16 + (c & 1) * 8;
                *(short8b*)&sL[off] = o;
            }
        }
        __syncthreads();

        short* dst = Hsb + (size_t)b * (L_ * DH_) + (size_t)(c0 >> 6) * 16384;
#pragma unroll
        for (int k = 0; k < 8; ++k) {
            const int idx = k * 2048 + tid * 8;
            *(short8b*)&dst[idx] = *(const short8b*)&sL[idx];
        }
    }
}

// ---------------------------------------------------------------------------
// attn_pipe5<LSPLIT> (unchanged from R13 — passing)
// ---------------------------------------------------------------------------
template <int LSPLIT>
__global__ __launch_bounds__(256, 2) void attn_pipe5(const short* __restrict__ Hsb,
                                                     const short* __restrict__ Qb,
                                                     float* __restrict__ Zdirect,
                                                     short* __restrict__ Zp,
                                                     float* __restrict__ Sp) {
    constexpr int LSB = (LSPLIT == 8) ? 3 : (LSPLIT == 4) ? 2 : (LSPLIT == 2) ? 1 : 0;

    __shared__ short sbuf[2][16384];

    const int wg   = blockIdx.x;
    const int low  = wg & 7;
    const int rest = wg >> 3;
    const int tg   = rest & 3;
    const int ghi  = rest >> 2;
    const int grp  = ghi * 8 + low;
    const int b    = grp >> LSB;
    const int lq   = grp & (LSPLIT - 1);

    const int tid  = threadIdx.x;
    const int wid  = tid >> 6;
    const int lane = tid & 63;
    const int l15  = lane & 15, g = lane >> 4;
    const int th   = wid;
    const int t0   = tg * 128;

    const int cnt      = g_cnt[b];
    const int nt_total = (cnt + 63) >> 6;
    const int q        = (nt_total + LSPLIT - 1) >> LSB;
    const int start    = lq * q;
    int ntiles = nt_total - start;
    ntiles = ntiles < 0 ? 0 : (ntiles > q ? q : ntiles);

    const short* Hb = Hsb + (size_t)b * (L_ * DH_);

    short8b qf[2][8];
#pragma unroll
    for (int nt = 0; nt < 2; ++nt) {
        const short* qrow = Qb + ((size_t)b * T_ + t0 + th * 32 + nt * 16 + l15) * DP_;
#pragma unroll
        for (int ks = 0; ks < 8; ++ks)
            qf[nt][ks] = *(const short8b*)&qrow[ks * 32 + g * 8];
    }

    f32x4 zacc[2][16];
#pragma unroll
    for (int nt = 0; nt < 2; ++nt)
#pragma unroll
        for (int nf = 0; nf < 16; ++nf)
            zacc[nt][nf] = (f32x4){0.f, 0.f, 0.f, 0.f};
    float s_part[2] = {0.f, 0.f};

    const int  idx0  = (l15 + 32 * (g & 1)) * 4;
    const int  idx1  = idx0 + 64;
    const bool ltsel = (g >> 1) != 0;

    lds_short* trb0 = (lds_short*)&sbuf[0][0] + (lane >> 4) * 2048 + (lane & 15) * 4;
    lds_short* trb1 = (lds_short*)&sbuf[1][0] + (lane >> 4) * 2048 + (lane & 15) * 4;

    auto STAGE = [&](int bi, int gi) {
        const int gic = gi < 127 ? gi : 127;
        const short* src = Hb + (size_t)gic * 16384;
#pragma unroll
        for (int c = 0; c < 8; ++c) {
            const int u = wid * 512 + c * 64 + lane;
            GLOAD_LDS16(src + u * 8, &sbuf[bi][u * 8]);
        }
    };

    if (ntiles > 0) {
        STAGE(0, start);
        asm volatile("s_waitcnt vmcnt(0)" ::: "memory");
        __builtin_amdgcn_s_barrier();
        STAGE(1, start + 1);

        for (int i = 0; i < ntiles; ++i) {
            const int cur = i & 1;
            const short* sK = &sbuf[cur][0];
            const int gi = start + i;
            const int limit = cnt - (gi << 6);

            // ---- S^T phase (two halves) ----
            unsigned pk[4][2][2];
#pragma unroll
            for (int lh2 = 0; lh2 < 2; ++lh2) {
                f32x4 sv[2][2];
#pragma unroll
                for (int ltl = 0; ltl < 2; ++ltl)
#pragma unroll
                    for (int nt = 0; nt < 2; ++nt)
                        sv[ltl][nt] = (f32x4){0.f, 0.f, 0.f, 0.f};
                __builtin_amdgcn_s_setprio(1);
#pragma unroll
                for (int ltl = 0; ltl < 2; ++ltl) {
                    const int lt = lh2 * 2 + ltl;
#pragma unroll
                    for (int ks = 0; ks < 8; ++ks) {
                        short8b af = *(const short8b*)&sK[(lt * 4 + (l15 >> 2)) * 1024 +
                                                          (ks * 2 + (g >> 1)) * 64 +
                                                          (l15 & 3) * 16 + (g & 1) * 8];
                        sv[ltl][0] = __builtin_amdgcn_mfma_f32_16x16x32_bf16(af, qf[0][ks], sv[ltl][0], 0, 0, 0);
                        sv[ltl][1] = __builtin_amdgcn_mfma_f32_16x16x32_bf16(af, qf[1][ks], sv[ltl][1], 0, 0, 0);
                    }
                }
                __builtin_amdgcn_s_setprio(0);

                if (limit >= 64) {
#pragma unroll
                    for (int ltl = 0; ltl < 2; ++ltl)
#pragma unroll
                        for (int nt = 0; nt < 2; ++nt) {
                            float p0 = exp2_raw(sv[ltl][nt][0]);
                            float p1 = exp2_raw(sv[ltl][nt][1]);
                            float p2 = exp2_raw(sv[ltl][nt][2]);
                            float p3 = exp2_raw(sv[ltl][nt][3]);
                            s_part[nt] += (p0 + p1) + (p2 + p3);
                            pk[lh2 * 2 + ltl][nt][0] = cvtpk_bf16(p0, p1);
                            pk[lh2 * 2 + ltl][nt][1] = cvtpk_bf16(p2, p3);
                        }
                } else {
#pragma unroll
                    for (int ltl = 0; ltl < 2; ++ltl) {
                        const int lt = lh2 * 2 + ltl;
                        const int thr = limit - lt * 16 - 4 * g;
                        float madd[4];
#pragma unroll
                        for (int r = 0; r < 4; ++r) madd[r] = (r < thr) ? 0.f : -INFINITY;
#pragma unroll
                        for (int nt = 0; nt < 2; ++nt) {
                            float p0 = exp2_raw(sv[ltl][nt][0] + madd[0]);
                            float p1 = exp2_raw(sv[ltl][nt][1] + madd[1]);
                            float p2 = exp2_raw(sv[ltl][nt][2] + madd[2]);
                            float p3 = exp2_raw(sv[ltl][nt][3] + madd[3]);
                            s_part[nt] += (p0 + p1) + (p2 + p3);
                            pk[lt][nt][0] = cvtpk_bf16(p0, p1);
                            pk[lt][nt][1] = cvtpk_bf16(p2, p3);
                        }
                    }
                }
            }

            // ---- P -> PV A-frags ----
            short8b pa[2][2];
#pragma unroll
            for (int h = 0; h < 2; ++h)
#pragma unroll
                for (int nt = 0; nt < 2; ++nt) {
                    int A0 = __builtin_amdgcn_ds_bpermute(idx0, (int)pk[2 * h][nt][0]);
                    int A1 = __builtin_amdgcn_ds_bpermute(idx0, (int)pk[2 * h][nt][1]);
                    int B0 = __builtin_amdgcn_ds_bpermute(idx0, (int)pk[2 * h + 1][nt][0]);
                    int B1 = __builtin_amdgcn_ds_bpermute(idx0, (int)pk[2 * h + 1][nt][1]);
                    int C0 = __builtin_amdgcn_ds_bpermute(idx1, (int)pk[2 * h][nt][0]);
                    int C1 = __builtin_amdgcn_ds_bpermute(idx1, (int)pk[2 * h][nt][1]);
                    int D0 = __builtin_amdgcn_ds_bpermute(idx1, (int)pk[2 * h + 1][nt][0]);
                    int D1 = __builtin_amdgcn_ds_bpermute(idx1, (int)pk[2 * h + 1][nt][1]);
                    union { int d[4]; short8b v; } u;
                    u.d[0] = ltsel ? B0 : A0;
                    u.d[1] = ltsel ? B1 : A1;
                    u.d[2] = ltsel ? D0 : C0;
                    u.d[3] = ltsel ? D1 : C1;
                    pa[h][nt] = u.v;
                }

            // ---- PV: tr-read pipelined (2 deep) ----
            lds_short* ptr = cur ? trb1 : trb0;
            short4b tb[2][4];
            TRR(tb[0][0], ptr, 0 * 2048);
            TRR(tb[0][1], ptr, 1 * 2048);
            TRR(tb[0][2], ptr, 8 * 2048);
            TRR(tb[0][3], ptr, 9 * 2048);
            __builtin_amdgcn_s_setprio(1);
#pragma unroll
            for (int nf = 0; nf < 16; ++nf) {
                if (nf < 15) {
                    TRR(tb[(nf + 1) & 1][0], ptr, 0 * 2048 + (nf + 1) * 128);
                    TRR(tb[(nf + 1) & 1][1], ptr, 1 * 2048 + (nf + 1) * 128);
                    TRR(tb[(nf + 1) & 1][2], ptr, 8 * 2048 + (nf + 1) * 128);
                    TRR(tb[(nf + 1) & 1][3], ptr, 9 * 2048 + (nf + 1) * 128);
                    asm volatile("s_waitcnt lgkmcnt(4)" ::: "memory");
                } else {
                    asm volatile("s_waitcnt lgkmcnt(0)" ::: "memory");
                }
                __builtin_amdgcn_sched_barrier(0);
#pragma unroll
                for (int h = 0; h < 2; ++h) {
                    short8b hb = __builtin_shufflevector(tb[nf & 1][2 * h], tb[nf & 1][2 * h + 1],
                                                         0, 1, 2, 3, 4, 5, 6, 7);
                    zacc[0][nf] = __builtin_amdgcn_mfma_f32_16x16x32_bf16(pa[h][0], hb, zacc[0][nf], 0, 0, 0);
                    zacc[1][nf] = __builtin_amdgcn_mfma_f32_16x16x32_bf16(pa[h][1], hb, zacc[1][nf], 0, 0, 0);
                }
            }
            __builtin_amdgcn_s_setprio(0);

            asm volatile("s_waitcnt vmcnt(0)" ::: "memory");
            __builtin_amdgcn_s_barrier();
            if (i + 2 < ntiles) STAGE(cur, gi + 2);
        }
    }

    // ---- epilogue ----
    float sful[2];
#pragma unroll
    for (int nt = 0; nt < 2; ++nt) {
        float v = s_part[nt];
        v += __shfl_xor(v, 16, 64);
        v += __shfl_xor(v, 32, 64);
        sful[nt] = v;
    }

    if constexpr (LSPLIT == 1) {
#pragma unroll
        for (int nt = 0; nt < 2; ++nt)
#pragma unroll
            for (int r = 0; r < 4; ++r) {
                float s = __shfl(sful[nt], 4 * g + r, 64);
                float ri = (s > 0.f) ? 1.f / s : 0.f;
                float* zrow = Zdirect + ((size_t)b * T_ + t0 + th * 32 + nt * 16 + 4 * g + r) * DH_;
#pragma unroll
                for (int nf = 0; nf < 16; ++nf)
                    zrow[nf * 16 + l15] = zacc[nt][nf][r] * ri;
            }
    } else {
        const int pb = (b * 4 + tg) * LSPLIT + lq;
        if (lane < 16) {
            Sp[(size_t)pb * 128 + th * 32 + l15]      = sful[0];
            Sp[(size_t)pb * 128 + th * 32 + 16 + l15] = sful[1];
        }
#pragma unroll
        for (int nt = 0; nt < 2; ++nt)
#pragma unroll
            for (int r = 0; r < 4; ++r) {
                short* zrow = Zp + ((size_t)pb * 128 + th * 32 + nt * 16 + 4 * g + r) * DH_;
#pragma unroll
                for (int nf = 0; nf < 16; ++nf)
                    zrow[nf * 16 + l15] = f2bf(zacc[nt][nf][r]);
            }
    }
}

// ---------------------------------------------------------------------------
// combine_z<LSPLIT> (unchanged — passing)
// ---------------------------------------------------------------------------
template <int LSPLIT>
__global__ __launch_bounds__(256) void combine_z(const short* __restrict__ Zp,
                                                 const float* __restrict__ Sp,
                                                 float* __restrict__ Z) {
    const int idx8 = blockIdx.x * 256 + threadIdx.x;
    const int d0 = (idx8 & 31) * 8;
    const int t  = (idx8 >> 5) & 511;
    const int b  = idx8 >> 14;
    const int tg = t >> 7, tl = t & 127;
    const size_t pb0 = (size_t)(b * 4 + tg) * LSPLIT;

    float acc[8] = {0.f, 0.f, 0.f, 0.f, 0.f, 0.f, 0.f, 0.f};
    float s = 0.f;
#pragma unroll
    for (int lq = 0; lq < LSPLIT; ++lq) {
        short8b v = *(const short8b*)&Zp[((pb0 + lq) * 128 + tl) * 256 + d0];
#pragma unroll
        for (int j = 0; j < 8; ++j) acc[j] += bf2f(v[j]);
        s += Sp[(pb0 + lq) * 128 + tl];
    }
    const float ri = (s > 0.f) ? 1.f / s : 0.f;
    float* zrow = Z + (((size_t)b * T_ + t) * DH_ + d0);
    *(float4*)zrow       = make_float4(acc[0] * ri, acc[1] * ri, acc[2] * ri, acc[3] * ri);
    *(float4*)(zrow + 4) = make_float4(acc[4] * ri, acc[5] * ri, acc[6] * ri, acc[7] * ri);
}

// ---------------------------------------------------------------------------
extern "C" void kernel_launch(void* const* d_in, const int* in_sizes, int n_in,
                              void* d_out, int out_size, void* d_ws, size_t ws_size,
                              hipStream_t stream) {
    const float* H    = (const float*)d_in[0];
    const float* G    = (const float*)d_in[1];
    const int*   mask = (const int*)d_in[2];
    const float* Wk   = (const float*)d_in[3];
    const float* Wq   = (const float*)d_in[4];
    float* Z = (float*)d_out;

    short* Wktf = (short*)d_ws;                 //   128 KB (Wk^T B-frags)
    short* Wqf  = Wktf + 65536ull;              //   256 KB
    short* Hsb  = Wqf + 131072ull;              //  67.1 MB (subtiled bf16 H, compacted)
    short* Qc   = Hsb + 33554432ull;            //   4.2 MB
    short* Htc  = Qc + 2097152ull;              //  67.1 MB (UNUSED — layout anchor)
    short* Zpb  = Htc + 33554432ull;            //  bf16 partials (LSPLIT*16.8MB)

    const float alpha_q = 1.4426950408889634f / 16.0f;  // DP^-0.5 * log2(e)

    prep_all<<<dim3(40), 1024, 0, stream>>>(mask, Wk, Wq, Wktf, Wqf, alpha_q);
    produce_all<<<dim3(128 + B_ * 128), 256, 0, stream>>>(G, Wqf, Wktf, Qc, H, Hsb);

    const size_t base = 138805248ull;  // bytes up to Zpb (same anchor as R9-R13)
    if (ws_size >= base + 8388608ull * 8 + 262144ull) {
        float* Sp = (float*)(Zpb + (size_t)64 * 8 * 128 * 256);
        attn_pipe5<8><<<dim3(512), 256, 0, stream>>>(Hsb, Qc, Z, Zpb, Sp);
        combine_z<8><<<dim3(1024), 256, 0, stream>>>(Zpb, Sp, Z);
    } else if (ws_size >= base + 8388608ull * 4 + 131072ull) {
        float* Sp = (float*)(Zpb + (size_t)64 * 4 * 128 * 256);
        attn_pipe5<4><<<dim3(256), 256, 0, stream>>>(Hsb, Qc, Z, Zpb, Sp);
        combine_z<4><<<dim3(1024), 256, 0, stream>>>(Zpb, Sp, Z);
    } else if (ws_size >= base + 8388608ull * 2 + 65536ull) {
        float* Sp = (float*)(Zpb + (size_t)64 * 2 * 128 * 256);
        attn_pipe5<2><<<dim3(128), 256, 0, stream>>>(Hsb, Qc, Z, Zpb, Sp);
        combine_z<2><<<dim3(1024), 256, 0, stream>>>(Zpb, Sp, Z);
    } else {
        attn_pipe5<1><<<dim3(64), 256, 0, stream>>>(Hsb, Qc, Z, Zpb, nullptr);
    }
}

// Round 15
// 101.032 us; speedup vs baseline: 1.4421x; 1.0396x over previous
//
#include <hip/hip_runtime.h>
#include <hip/hip_bf16.h>
#include <math.h>

#define B_  16
#define L_  8192
#define DH_ 256
#define T_  512
#define DG_ 512
#define DP_ 256

typedef __attribute__((ext_vector_type(8))) short short8b;
typedef __attribute__((ext_vector_type(4))) short short4b;
typedef __attribute__((ext_vector_type(4))) float f32x4;

typedef const __attribute__((address_space(1))) void gas_t;
typedef __attribute__((address_space(3))) void las_t;
typedef __attribute__((address_space(3))) short lds_short;
#define GLOAD_LDS16(g, l) __builtin_amdgcn_global_load_lds((gas_t*)(g), (las_t*)(l), 16, 0, 0)

// tr-read semantics (m156/m162): each lane reads 8B at its OWN address
// (subtile_base + (lane&15)*8 bytes); HW redistributes within each 16-lane
// group: out lane l elem j = the group's 64-elem block element (l&15)+j*16.
#define TRR(dst, P, OFF) \
    asm volatile("ds_read_b64_tr_b16 %0, %1 offset:%c2" : "=v"(dst) : "v"(P), "i"(OFF))

// Compaction metadata. g_dst[b][l] = compacted destination index of source
// row l (valid only where mask==0). Rewritten every launch -> deterministic.
__device__ int g_cnt[B_];
__device__ int g_dst[B_][L_];

static __device__ __forceinline__ short f2bf(float f) {
    union { __hip_bfloat16 b; short s; } u;
    u.b = __float2bfloat16(f);
    return u.s;
}

static __device__ __forceinline__ float bf2f(short s) {
    union { float f; unsigned u; } v;
    v.u = ((unsigned)(unsigned short)s) << 16;
    return v.f;
}

static __device__ __forceinline__ unsigned cvtpk_bf16(float lo, float hi) {
    unsigned r;
    asm("v_cvt_pk_bf16_f32 %0, %1, %2" : "=v"(r) : "v"(lo), "v"(hi));
    return r;
}

static __device__ __forceinline__ float exp2_raw(float x) {
    float r;
    asm("v_exp_f32 %0, %1" : "=v"(r) : "v"(x));
    return r;
}

static __device__ __forceinline__ short8b cvt8(const float* __restrict__ src) {
    float4 a = *(const float4*)src;
    float4 b = *(const float4*)(src + 4);
    short8b o;
    o[0] = f2bf(a.x); o[1] = f2bf(a.y); o[2] = f2bf(a.z); o[3] = f2bf(a.w);
    o[4] = f2bf(b.x); o[5] = f2bf(b.y); o[6] = f2bf(b.z); o[7] = f2bf(b.w);
    return o;
}

// ---------------------------------------------------------------------------
// prep_all: scan now records g_dst (dest index per kept source row).
// ---------------------------------------------------------------------------
__global__ __launch_bounds__(1024) void prep_all(const int* __restrict__ mask,
                                                 const float* __restrict__ Wk,
                                                 const float* __restrict__ Wq,
                                                 short* __restrict__ Wktf,
                                                 short* __restrict__ Wqf,
                                                 float alpha_q) {
    const int blk = blockIdx.x;
    const int tid = threadIdx.x, lane = tid & 63;
    const int l15 = lane & 15, g = lane >> 4;

    if (blk < 16) {
        const int b = blk, wid = tid >> 6;
        __shared__ int wsum[16];
        const int* mb = mask + (size_t)b * L_;
        int base = 0;
        for (int it = 0; it < L_ / 1024; ++it) {
            const int l = it * 1024 + tid;
            const int um = (mb[l] == 0);
            unsigned long long bal = __ballot(um);
            const int below = __popcll(bal & ((1ull << lane) - 1ull));
            const int wtot  = __popcll(bal);
            if (lane == 0) wsum[wid] = wtot;
            __syncthreads();
            int wbase = 0, tot = 0;
#pragma unroll
            for (int w = 0; w < 16; ++w) {
                wbase += (w < wid) ? wsum[w] : 0;
                tot   += wsum[w];
            }
            if (um) g_dst[b][l] = base + wbase + below;
            base += tot;
            __syncthreads();
        }
        if (tid == 0) g_cnt[b] = base;
    } else if (blk < 24) {
        const int f = (blk - 16) * 16 + (tid >> 6);   // 0..127
        const int nf = f >> 3, ks = f & 7;
        short8b o;
#pragma unroll
        for (int j = 0; j < 8; ++j)
            o[j] = f2bf(Wk[(size_t)(ks * 32 + g * 8 + j) * DH_ + nf * 16 + l15]);
        *(short8b*)&Wktf[(size_t)f * 512 + lane * 8] = o;
    } else {
        const int f = (blk - 24) * 16 + (tid >> 6);   // 0..255
        const int nf = f >> 4, ks = f & 15;
        const float* src = Wq + (size_t)(nf * 16 + l15) * DG_ + ks * 32 + g * 8;
        short8b o;
#pragma unroll
        for (int j = 0; j < 8; ++j) o[j] = f2bf(src[j] * alpha_q);
        *(short8b*)&Wqf[(size_t)f * 512 + lane * 8] = o;
    }
}

// ---------------------------------------------------------------------------
// produce_all: projQfused (blocks 0..127) + STREAM-COMPACT H (blocks 128+).
// Compaction inverted vs R14: block reads 64 CONSECUTIVE SOURCE rows
// (sequential, prefetch-friendly; skips masked rows), converts, and
// scatter-writes each 16B piece straight to the subtiled compacted slot
// (dest idx from g_dst). Writes are fire-and-forget; L2 merges neighboring
// dest rows into full lines. No LDS, no barrier in this path. Pad rows
// [cnt, padded) stay unwritten: attn's tail masking zeroes their P, so
// their (finite) garbage never reaches Z.
// Hsub per-b: tile(dl>>6)*16384 shorts; within tile:
// (dl>>2)*1024 + (d>>4)*64 + (dl&3)*16 + (d&15).
// ---------------------------------------------------------------------------
__global__ __launch_bounds__(256) void produce_all(const float* __restrict__ G,
                                                   const short* __restrict__ Wqf,
                                                   const short* __restrict__ Wktf,
                                                   short* __restrict__ Qc,
                                                   const float* __restrict__ H,
                                                   const int* __restrict__ mask,
                                                   short* __restrict__ Hsb) {
    __shared__ short sL[16896];

    const int blk = blockIdx.x;
    const int tid = threadIdx.x;

    if (blk < 128) {
        // ---- projQfused path: Qc = bf16(bf16(aG@Wq^T)@Wk) ----
        const int wid = tid >> 6, lane = tid & 63;
        const int l15 = lane & 15, g = lane >> 4;
        const size_t m0 = (size_t)blk * 64;

        const float* arow = G + (m0 + wid * 16 + l15) * DG_;
        short8b af[16];
#pragma unroll
        for (int ks = 0; ks < 16; ++ks) {
            float4 a = *(const float4*)&arow[ks * 32 + g * 8];
            float4 c = *(const float4*)&arow[ks * 32 + g * 8 + 4];
            short8b o;
            o[0] = f2bf(a.x); o[1] = f2bf(a.y); o[2] = f2bf(a.z); o[3] = f2bf(a.w);
            o[4] = f2bf(c.x); o[5] = f2bf(c.y); o[6] = f2bf(c.z); o[7] = f2bf(c.w);
            af[ks] = o;
        }
        f32x4 acc[16];
#pragma unroll
        for (int i = 0; i < 16; ++i) acc[i] = (f32x4){0.f, 0.f, 0.f, 0.f};
#pragma unroll
        for (int ks = 0; ks < 16; ++ks)
#pragma unroll
            for (int nf = 0; nf < 16; ++nf) {
                short8b wf = *(const short8b*)&Wqf[(size_t)(nf * 16 + ks) * 512 + lane * 8];
                acc[nf] = __builtin_amdgcn_mfma_f32_16x16x32_bf16(af[ks], wf, acc[nf], 0, 0, 0);
            }
#pragma unroll
        for (int nf = 0; nf < 16; ++nf)
#pragma unroll
            for (int r = 0; r < 4; ++r)
                sL[(wid * 16 + 4 * g + r) * 264 + nf * 16 + l15] = f2bf(acc[nf][r]);
        __syncthreads();

        short8b af2[8];
#pragma unroll
        for (int ks = 0; ks < 8; ++ks)
            af2[ks] = *(const short8b*)&sL[(wid * 16 + l15) * 264 + ks * 32 + g * 8];
        f32x4 acc2[16];
#pragma unroll
        for (int i = 0; i < 16; ++i) acc2[i] = (f32x4){0.f, 0.f, 0.f, 0.f};
#pragma unroll
        for (int ks = 0; ks < 8; ++ks)
#pragma unroll
            for (int nf = 0; nf < 16; ++nf) {
                short8b wf = *(const short8b*)&Wktf[(size_t)(nf * 8 + ks) * 512 + lane * 8];
                acc2[nf] = __builtin_amdgcn_mfma_f32_16x16x32_bf16(af2[ks], wf, acc2[nf], 0, 0, 0);
            }
#pragma unroll
        for (int nf = 0; nf < 16; ++nf)
#pragma unroll
            for (int r = 0; r < 4; ++r)
                Qc[(m0 + wid * 16 + 4 * g + r) * DP_ + nf * 16 + l15] = f2bf(acc2[nf][r]);
    } else {
        // ---- stream-compact path ----
        const int gb = blk - 128;
        const int b  = gb >> 7;
        const int c0 = (gb & 127) * 64;
        const int r = tid >> 2, sub = tid & 3;
        const int l = c0 + r;

        if (mask[(size_t)b * L_ + l] != 0) return;   // masked: no work

        const int dld = g_dst[b][l];
        const int dl  = dld & 63;
        short* dtile = Hsb + (size_t)b * (L_ * DH_) + (size_t)(dld >> 6) * 16384
                     + (dl >> 2) * 1024 + (dl & 3) * 16;
        const float* src = H + ((size_t)b * L_ + l) * DH_;
#pragma unroll
        for (int j = 0; j < 8; ++j) {
            const int c = j * 4 + sub;               // 32B chunk: d = c*8 .. c*8+7
            short8b o = cvt8(&src[c * 8]);
            *(short8b*)&dtile[(c >> 1) * 64 + (c & 1) * 8] = o;
        }
    }
}

// ---------------------------------------------------------------------------
// attn_pipe5<LSPLIT> (unchanged from R13/R14 — passing)
// ---------------------------------------------------------------------------
template <int LSPLIT>
__global__ __launch_bounds__(256, 2) void attn_pipe5(const short* __restrict__ Hsb,
                                                     const short* __restrict__ Qb,
                                                     float* __restrict__ Zdirect,
                                                     short* __restrict__ Zp,
                                                     float* __restrict__ Sp) {
    constexpr int LSB = (LSPLIT == 8) ? 3 : (LSPLIT == 4) ? 2 : (LSPLIT == 2) ? 1 : 0;

    __shared__ short sbuf[2][16384];

    const int wg   = blockIdx.x;
    const int low  = wg & 7;
    const int rest = wg >> 3;
    const int tg   = rest & 3;
    const int ghi  = rest >> 2;
    const int grp  = ghi * 8 + low;
    const int b    = grp >> LSB;
    const int lq   = grp & (LSPLIT - 1);

    const int tid  = threadIdx.x;
    const int wid  = tid >> 6;
    const int lane = tid & 63;
    const int l15  = lane & 15, g = lane >> 4;
    const int th   = wid;
    const int t0   = tg * 128;

    const int cnt      = g_cnt[b];
    const int nt_total = (cnt + 63) >> 6;
    const int q        = (nt_total + LSPLIT - 1) >> LSB;
    const int start    = lq * q;
    int ntiles = nt_total - start;
    ntiles = ntiles < 0 ? 0 : (ntiles > q ? q : ntiles);

    const short* Hb = Hsb + (size_t)b * (L_ * DH_);

    short8b qf[2][8];
#pragma unroll
    for (int nt = 0; nt < 2; ++nt) {
        const short* qrow = Qb + ((size_t)b * T_ + t0 + th * 32 + nt * 16 + l15) * DP_;
#pragma unroll
        for (int ks = 0; ks < 8; ++ks)
            qf[nt][ks] = *(const short8b*)&qrow[ks * 32 + g * 8];
    }

    f32x4 zacc[2][16];
#pragma unroll
    for (int nt = 0; nt < 2; ++nt)
#pragma unroll
        for (int nf = 0; nf < 16; ++nf)
            zacc[nt][nf] = (f32x4){0.f, 0.f, 0.f, 0.f};
    float s_part[2] = {0.f, 0.f};

    const int  idx0  = (l15 + 32 * (g & 1)) * 4;
    const int  idx1  = idx0 + 64;
    const bool ltsel = (g >> 1) != 0;

    lds_short* trb0 = (lds_short*)&sbuf[0][0] + (lane >> 4) * 2048 + (lane & 15) * 4;
    lds_short* trb1 = (lds_short*)&sbuf[1][0] + (lane >> 4) * 2048 + (lane & 15) * 4;

    auto STAGE = [&](int bi, int gi) {
        const int gic = gi < 127 ? gi : 127;
        const short* src = Hb + (size_t)gic * 16384;
#pragma unroll
        for (int c = 0; c < 8; ++c) {
            const int u = wid * 512 + c * 64 + lane;
            GLOAD_LDS16(src + u * 8, &sbuf[bi][u * 8]);
        }
    };

    if (ntiles > 0) {
        STAGE(0, start);
        asm volatile("s_waitcnt vmcnt(0)" ::: "memory");
        __builtin_amdgcn_s_barrier();
        STAGE(1, start + 1);

        for (int i = 0; i < ntiles; ++i) {
            const int cur = i & 1;
            const short* sK = &sbuf[cur][0];
            const int gi = start + i;
            const int limit = cnt - (gi << 6);

            // ---- S^T phase (two halves) ----
            unsigned pk[4][2][2];
#pragma unroll
            for (int lh2 = 0; lh2 < 2; ++lh2) {
                f32x4 sv[2][2];
#pragma unroll
                for (int ltl = 0; ltl < 2; ++ltl)
#pragma unroll
                    for (int nt = 0; nt < 2; ++nt)
                        sv[ltl][nt] = (f32x4){0.f, 0.f, 0.f, 0.f};
                __builtin_amdgcn_s_setprio(1);
#pragma unroll
                for (int ltl = 0; ltl < 2; ++ltl) {
                    const int lt = lh2 * 2 + ltl;
#pragma unroll
                    for (int ks = 0; ks < 8; ++ks) {
                        short8b af = *(const short8b*)&sK[(lt * 4 + (l15 >> 2)) * 1024 +
                                                          (ks * 2 + (g >> 1)) * 64 +
                                                          (l15 & 3) * 16 + (g & 1) * 8];
                        sv[ltl][0] = __builtin_amdgcn_mfma_f32_16x16x32_bf16(af, qf[0][ks], sv[ltl][0], 0, 0, 0);
                        sv[ltl][1] = __builtin_amdgcn_mfma_f32_16x16x32_bf16(af, qf[1][ks], sv[ltl][1], 0, 0, 0);
                    }
                }
                __builtin_amdgcn_s_setprio(0);

                if (limit >= 64) {
#pragma unroll
                    for (int ltl = 0; ltl < 2; ++ltl)
#pragma unroll
                        for (int nt = 0; nt < 2; ++nt) {
                            float p0 = exp2_raw(sv[ltl][nt][0]);
                            float p1 = exp2_raw(sv[ltl][nt][1]);
                            float p2 = exp2_raw(sv[ltl][nt][2]);
                            float p3 = exp2_raw(sv[ltl][nt][3]);
                            s_part[nt] += (p0 + p1) + (p2 + p3);
                            pk[lh2 * 2 + ltl][nt][0] = cvtpk_bf16(p0, p1);
                            pk[lh2 * 2 + ltl][nt][1] = cvtpk_bf16(p2, p3);
                        }
                } else {
#pragma unroll
                    for (int ltl = 0; ltl < 2; ++ltl) {
                        const int lt = lh2 * 2 + ltl;
                        const int thr = limit - lt * 16 - 4 * g;
                        float madd[4];
#pragma unroll
                        for (int r = 0; r < 4; ++r) madd[r] = (r < thr) ? 0.f : -INFINITY;
#pragma unroll
                        for (int nt = 0; nt < 2; ++nt) {
                            float p0 = exp2_raw(sv[ltl][nt][0] + madd[0]);
                            float p1 = exp2_raw(sv[ltl][nt][1] + madd[1]);
                            float p2 = exp2_raw(sv[ltl][nt][2] + madd[2]);
                            float p3 = exp2_raw(sv[ltl][nt][3] + madd[3]);
                            s_part[nt] += (p0 + p1) + (p2 + p3);
                            pk[lt][nt][0] = cvtpk_bf16(p0, p1);
                            pk[lt][nt][1] = cvtpk_bf16(p2, p3);
                        }
                    }
                }
            }

            // ---- P -> PV A-frags ----
            short8b pa[2][2];
#pragma unroll
            for (int h = 0; h < 2; ++h)
#pragma unroll
                for (int nt = 0; nt < 2; ++nt) {
                    int A0 = __builtin_amdgcn_ds_bpermute(idx0, (int)pk[2 * h][nt][0]);
                    int A1 = __builtin_amdgcn_ds_bpermute(idx0, (int)pk[2 * h][nt][1]);
                    int B0 = __builtin_amdgcn_ds_bpermute(idx0, (int)pk[2 * h + 1][nt][0]);
                    int B1 = __builtin_amdgcn_ds_bpermute(idx0, (int)pk[2 * h + 1][nt][1]);
                    int C0 = __builtin_amdgcn_ds_bpermute(idx1, (int)pk[2 * h][nt][0]);
                    int C1 = __builtin_amdgcn_ds_bpermute(idx1, (int)pk[2 * h][nt][1]);
                    int D0 = __builtin_amdgcn_ds_bpermute(idx1, (int)pk[2 * h + 1][nt][0]);
                    int D1 = __builtin_amdgcn_ds_bpermute(idx1, (int)pk[2 * h + 1][nt][1]);
                    union { int d[4]; short8b v; } u;
                    u.d[0] = ltsel ? B0 : A0;
                    u.d[1] = ltsel ? B1 : A1;
                    u.d[2] = ltsel ? D0 : C0;
                    u.d[3] = ltsel ? D1 : C1;
                    pa[h][nt] = u.v;
                }

            // ---- PV: tr-read pipelined (2 deep) ----
            lds_short* ptr = cur ? trb1 : trb0;
            short4b tb[2][4];
            TRR(tb[0][0], ptr, 0 * 2048);
            TRR(tb[0][1], ptr, 1 * 2048);
            TRR(tb[0][2], ptr, 8 * 2048);
            TRR(tb[0][3], ptr, 9 * 2048);
            __builtin_amdgcn_s_setprio(1);
#pragma unroll
            for (int nf = 0; nf < 16; ++nf) {
                if (nf < 15) {
                    TRR(tb[(nf + 1) & 1][0], ptr, 0 * 2048 + (nf + 1) * 128);
                    TRR(tb[(nf + 1) & 1][1], ptr, 1 * 2048 + (nf + 1) * 128);
                    TRR(tb[(nf + 1) & 1][2], ptr, 8 * 2048 + (nf + 1) * 128);
                    TRR(tb[(nf + 1) & 1][3], ptr, 9 * 2048 + (nf + 1) * 128);
                    asm volatile("s_waitcnt lgkmcnt(4)" ::: "memory");
                } else {
                    asm volatile("s_waitcnt lgkmcnt(0)" ::: "memory");
                }
                __builtin_amdgcn_sched_barrier(0);
#pragma unroll
                for (int h = 0; h < 2; ++h) {
                    short8b hb = __builtin_shufflevector(tb[nf & 1][2 * h], tb[nf & 1][2 * h + 1],
                                                         0, 1, 2, 3, 4, 5, 6, 7);
                    zacc[0][nf] = __builtin_amdgcn_mfma_f32_16x16x32_bf16(pa[h][0], hb, zacc[0][nf], 0, 0, 0);
                    zacc[1][nf] = __builtin_amdgcn_mfma_f32_16x16x32_bf16(pa[h][1], hb, zacc[1][nf], 0, 0, 0);
                }
            }
            __builtin_amdgcn_s_setprio(0);

            asm volatile("s_waitcnt vmcnt(0)" ::: "memory");
            __builtin_amdgcn_s_barrier();
            if (i + 2 < ntiles) STAGE(cur, gi + 2);
        }
    }

    // ---- epilogue ----
    float sful[2];
#pragma unroll
    for (int nt = 0; nt < 2; ++nt) {
        float v = s_part[nt];
        v += __shfl_xor(v, 16, 64);
        v += __shfl_xor(v, 32, 64);
        sful[nt] = v;
    }

    if constexpr (LSPLIT == 1) {
#pragma unroll
        for (int nt = 0; nt < 2; ++nt)
#pragma unroll
            for (int r = 0; r < 4; ++r) {
                float s = __shfl(sful[nt], 4 * g + r, 64);
                float ri = (s > 0.f) ? 1.f / s : 0.f;
                float* zrow = Zdirect + ((size_t)b * T_ + t0 + th * 32 + nt * 16 + 4 * g + r) * DH_;
#pragma unroll
                for (int nf = 0; nf < 16; ++nf)
                    zrow[nf * 16 + l15] = zacc[nt][nf][r] * ri;
            }
    } else {
        const int pb = (b * 4 + tg) * LSPLIT + lq;
        if (lane < 16) {
            Sp[(size_t)pb * 128 + th * 32 + l15]      = sful[0];
            Sp[(size_t)pb * 128 + th * 32 + 16 + l15] = sful[1];
        }
#pragma unroll
        for (int nt = 0; nt < 2; ++nt)
#pragma unroll
            for (int r = 0; r < 4; ++r) {
                short* zrow = Zp + ((size_t)pb * 128 + th * 32 + nt * 16 + 4 * g + r) * DH_;
#pragma unroll
                for (int nf = 0; nf < 16; ++nf)
                    zrow[nf * 16 + l15] = f2bf(zacc[nt][nf][r]);
            }
    }
}

// ---------------------------------------------------------------------------
// combine_z<LSPLIT> (unchanged — passing)
// ---------------------------------------------------------------------------
template <int LSPLIT>
__global__ __launch_bounds__(256) void combine_z(const short* __restrict__ Zp,
                                                 const float* __restrict__ Sp,
                                                 float* __restrict__ Z) {
    const int idx8 = blockIdx.x * 256 + threadIdx.x;
    const int d0 = (idx8 & 31) * 8;
    const int t  = (idx8 >> 5) & 511;
    const int b  = idx8 >> 14;
    const int tg = t >> 7, tl = t & 127;
    const size_t pb0 = (size_t)(b * 4 + tg) * LSPLIT;

    float acc[8] = {0.f, 0.f, 0.f, 0.f, 0.f, 0.f, 0.f, 0.f};
    float s = 0.f;
#pragma unroll
    for (int lq = 0; lq < LSPLIT; ++lq) {
        short8b v = *(const short8b*)&Zp[((pb0 + lq) * 128 + tl) * 256 + d0];
#pragma unroll
        for (int j = 0; j < 8; ++j) acc[j] += bf2f(v[j]);
        s += Sp[(pb0 + lq) * 128 + tl];
    }
    const float ri = (s > 0.f) ? 1.f / s : 0.f;
    float* zrow = Z + (((size_t)b * T_ + t) * DH_ + d0);
    *(float4*)zrow       = make_float4(acc[0] * ri, acc[1] * ri, acc[2] * ri, acc[3] * ri);
    *(float4*)(zrow + 4) = make_float4(acc[4] * ri, acc[5] * ri, acc[6] * ri, acc[7] * ri);
}

// ---------------------------------------------------------------------------
extern "C" void kernel_launch(void* const* d_in, const int* in_sizes, int n_in,
                              void* d_out, int out_size, void* d_ws, size_t ws_size,
                              hipStream_t stream) {
    const float* H    = (const float*)d_in[0];
    const float* G    = (const float*)d_in[1];
    const int*   mask = (const int*)d_in[2];
    const float* Wk   = (const float*)d_in[3];
    const float* Wq   = (const float*)d_in[4];
    float* Z = (float*)d_out;

    short* Wktf = (short*)d_ws;                 //   128 KB (Wk^T B-frags)
    short* Wqf  = Wktf + 65536ull;              //   256 KB
    short* Hsb  = Wqf + 131072ull;              //  67.1 MB (subtiled bf16 H, compacted)
    short* Qc   = Hsb + 33554432ull;            //   4.2 MB
    short* Htc  = Qc + 2097152ull;              //  67.1 MB (UNUSED — layout anchor)
    short* Zpb  = Htc + 33554432ull;            //  bf16 partials (LSPLIT*16.8MB)

    const float alpha_q = 1.4426950408889634f / 16.0f;  // DP^-0.5 * log2(e)

    prep_all<<<dim3(40), 1024, 0, stream>>>(mask, Wk, Wq, Wktf, Wqf, alpha_q);
    produce_all<<<dim3(128 + B_ * 128), 256, 0, stream>>>(G, Wqf, Wktf, Qc, H, mask, Hsb);

    const size_t base = 138805248ull;  // bytes up to Zpb (same anchor as R9-R14)
    if (ws_size >= base + 8388608ull * 8 + 262144ull) {
        float* Sp = (float*)(Zpb + (size_t)64 * 8 * 128 * 256);
        attn_pipe5<8><<<dim3(512), 256, 0, stream>>>(Hsb, Qc, Z, Zpb, Sp);
        combine_z<8><<<dim3(1024), 256, 0, stream>>>(Zpb, Sp, Z);
    } else if (ws_size >= base + 8388608ull * 4 + 131072ull) {
        float* Sp = (float*)(Zpb + (size_t)64 * 4 * 128 * 256);
        attn_pipe5<4><<<dim3(256), 256, 0, stream>>>(Hsb, Qc, Z, Zpb, Sp);
        combine_z<4><<<dim3(1024), 256, 0, stream>>>(Zpb, Sp, Z);
    } else if (ws_size >= base + 8388608ull * 2 + 65536ull) {
        float* Sp = (float*)(Zpb + (size_t)64 * 2 * 128 * 256);
        attn_pipe5<2><<<dim3(128), 256, 0, stream>>>(Hsb, Qc, Z, Zpb, Sp);
        combine_z<2><<<dim3(1024), 256, 0, stream>>>(Zpb, Sp, Z);
    } else {
        attn_pipe5<1><<<dim3(64), 256, 0, stream>>>(Hsb, Qc, Z, Zpb, nullptr);
    }
}